// Round 2
// baseline (1129.408 us; speedup 1.0000x reference)
//
#include <hip/hip_runtime.h>
#include <stdint.h>

#define DI static __device__ __forceinline__

typedef __attribute__((ext_vector_type(8))) short bf16x8;
typedef __attribute__((ext_vector_type(4))) float floatx4;

DI unsigned short f2bf(float x){
  unsigned int u = __float_as_uint(x);
  u += 0x7fffu + ((u >> 16) & 1u);
  return (unsigned short)(u >> 16);
}
DI float bf2f(unsigned short h){ return __uint_as_float(((unsigned int)h) << 16); }

#define GLOAD16(gp, lp) \
  __builtin_amdgcn_global_load_lds((const __attribute__((address_space(1))) unsigned int*)(gp), \
                                   (__attribute__((address_space(3))) unsigned int*)(lp), 16, 0, 0)

#define WAITVM(n) asm volatile("s_waitcnt vmcnt(" #n ")" ::: "memory")

// ---------------------------------------------------------------------------
// bf16 MFMA GEMM: C[M,N] = A[M,K] @ B[N,K]^T (+res), 128x128 tile, BK=32.
// LDS is kept in MFMA-fragment order: staging lane j loads global
// (row=j&15, kchunk=j>>4); fragment read = block*512 + lane*8 -> conflict-free.
// SPLIT: A,B are hi/lo bf16 pairs (lo at +aLo/+bLo elems): 3-pass MFMA ~fp32.
// OUTM: 0=f32 store, 1=bf16 store, 2=f32 atomicAdd (split-K via zb),
//       4=bf16 gh-epilogue (ew*silu(G1)*(acc+res)),
//       5=bf16 hi/lo pair store (+cLo), 6=pair store w/ V-transpose,
//       8=f32 partial store (split-K via zb, partial at zb*sC2)
// RESM: 0=none, 1=f32 residual, 2=bf16 residual (index m*ldr+n)
// CSKIP: skip tiles with blockIdx.y > blockIdx.x (causal)
// batching: zr=z&((1<<zshift)-1), zb=z>>zshift
// ---------------------------------------------------------------------------
template<int OUTM, int RESM, bool CSKIP, bool SPLIT>
__global__ __launch_bounds__(256, 2)
void k_gemm(const unsigned short* __restrict__ A, long lda, long sA1, long sA2, long aLo,
            const unsigned short* __restrict__ B, long ldb, long sB1, long sB2, long bLo,
            void* __restrict__ C, long ldc, long sC1, long sC2, long cLo,
            const void* __restrict__ Rz, long ldr,
            const unsigned short* __restrict__ G1p, const float* __restrict__ ewp, int slot,
            int kIters, int zshift, int bshift)
{
  if (CSKIP && blockIdx.y > blockIdx.x) return;
  __shared__ __attribute__((aligned(16))) unsigned short As[SPLIT ? 8192 : 4096];
  __shared__ __attribute__((aligned(16))) unsigned short Bs[SPLIT ? 8192 : 4096];
  const int tid = threadIdx.x;
  const int w = tid >> 6, lane = tid & 63;
  const int wm = (w >> 1) * 64, wn = (w & 1) * 64;
  const int z = blockIdx.z;
  const int zr = z & ((1 << zshift) - 1);
  const int zb = z >> zshift;
  long k0 = 0;
  if (OUTM == 2 || OUTM == 8) k0 = (long)zb * (long)kIters * 32;
  const unsigned short* Ab = A + (long)((OUTM==8)?0:zb) * sA2 + (long)zr * sA1 + (long)blockIdx.x * 128 * lda + k0;
  const unsigned short* Bb = B + (long)((OUTM==8)?0:zb) * sB2 + (long)(zr >> bshift) * sB1 + (long)blockIdx.y * 128 * ldb + k0;

  // fragment-order staging: lane j -> (row j&15, kchunk j>>4)
  const int rlo = w * 16 + (lane & 15);
  const int rhi = 64 + rlo;
  const int cc  = (lane >> 4) * 8;
  unsigned short* ldsA0 = As + w * 512;
  unsigned short* ldsA1 = As + 2048 + w * 512;
  unsigned short* ldsB0 = Bs + w * 512;
  unsigned short* ldsB1 = Bs + 2048 + w * 512;

  floatx4 acc[4][4];
  floatx4 zv = {0.f, 0.f, 0.f, 0.f};
#pragma unroll
  for (int i = 0; i < 4; ++i)
#pragma unroll
    for (int j = 0; j < 4; ++j) acc[i][j] = zv;

  const int abase = (wm >> 4) * 512 + lane * 8;
  const int bbase = (wn >> 4) * 512 + lane * 8;

  for (int kt = 0; kt < kIters; ++kt) {
    const unsigned short* pa = Ab + (long)kt * 32;
    const unsigned short* pb = Bb + (long)kt * 32;
    GLOAD16(pa + (long)rlo * lda + cc, ldsA0);
    GLOAD16(pa + (long)rhi * lda + cc, ldsA1);
    GLOAD16(pb + (long)rlo * ldb + cc, ldsB0);
    GLOAD16(pb + (long)rhi * ldb + cc, ldsB1);
    if (SPLIT) {
      const unsigned short* pal = pa + aLo;
      const unsigned short* pbl = pb + bLo;
      GLOAD16(pal + (long)rlo * lda + cc, As + 4096 + w * 512);
      GLOAD16(pal + (long)rhi * lda + cc, As + 6144 + w * 512);
      GLOAD16(pbl + (long)rlo * ldb + cc, Bs + 4096 + w * 512);
      GLOAD16(pbl + (long)rhi * ldb + cc, Bs + 6144 + w * 512);
    }
    __syncthreads();
    bf16x8 af[4], bfr[4];
#pragma unroll
    for (int i = 0; i < 4; ++i)
      af[i] = *(const bf16x8*)(As + abase + i * 512);
#pragma unroll
    for (int j = 0; j < 4; ++j)
      bfr[j] = *(const bf16x8*)(Bs + bbase + j * 512);
    if (SPLIT) {
      bf16x8 al[4], bl[4];
#pragma unroll
      for (int i = 0; i < 4; ++i)
        al[i] = *(const bf16x8*)(As + 4096 + abase + i * 512);
#pragma unroll
      for (int j = 0; j < 4; ++j)
        bl[j] = *(const bf16x8*)(Bs + 4096 + bbase + j * 512);
#pragma unroll
      for (int i = 0; i < 4; ++i)
#pragma unroll
        for (int j = 0; j < 4; ++j) {
          acc[i][j] = __builtin_amdgcn_mfma_f32_16x16x32_bf16(af[i], bfr[j], acc[i][j], 0, 0, 0);
          acc[i][j] = __builtin_amdgcn_mfma_f32_16x16x32_bf16(af[i], bl[j], acc[i][j], 0, 0, 0);
          acc[i][j] = __builtin_amdgcn_mfma_f32_16x16x32_bf16(al[i], bfr[j], acc[i][j], 0, 0, 0);
        }
    } else {
#pragma unroll
      for (int i = 0; i < 4; ++i)
#pragma unroll
        for (int j = 0; j < 4; ++j)
          acc[i][j] = __builtin_amdgcn_mfma_f32_16x16x32_bf16(af[i], bfr[j], acc[i][j], 0, 0, 0);
    }
    __syncthreads();
  }

  const long mb = (long)blockIdx.x * 128 + wm + ((lane >> 4) * 4);
  const long nb = (long)blockIdx.y * 128 + wn + (lane & 15);
  const long cbase = (long)zb * sC2 + (long)zr * sC1;
#pragma unroll
  for (int i = 0; i < 4; ++i) {
#pragma unroll
    for (int j = 0; j < 4; ++j) {
#pragma unroll
      for (int rr = 0; rr < 4; ++rr) {
        long m = mb + i * 16 + rr;
        long n = nb + j * 16;
        float v = acc[i][j][rr];
        if (RESM == 1) v += ((const float*)Rz)[m * ldr + n];
        if (RESM == 2) v += bf2f(((const unsigned short*)Rz)[m * ldr + n]);
        if (OUTM == 0 || OUTM == 8) ((float*)C)[cbase + m * ldc + n] = v;
        else if (OUTM == 1) ((unsigned short*)C)[cbase + m * ldc + n] = f2bf(v);
        else if (OUTM == 2) atomicAdd((float*)C + cbase + m * ldc + n, v);
        else if (OUTM == 4) {
          float g1 = bf2f(G1p[m * ldc + n]);
          float s1 = g1 / (1.f + __expf(-g1));
          ((unsigned short*)C)[cbase + m * ldc + n] = f2bf(ewp[m * 2 + slot] * s1 * v);
        } else if (OUTM == 5) {
          unsigned short h = f2bf(v);
          unsigned short l = f2bf(v - bf2f(h));
          ((unsigned short*)C)[cbase + m * ldc + n] = h;
          ((unsigned short*)C)[cbase + m * ldc + n + cLo] = l;
        } else {  // OUTM == 6
          long bq = m >> 9, sI = m & 511, kv = n >> 7, dI = n & 127;
          long t = (((bq * 4 + kv) * 128 + dI) << 9) + sI;
          unsigned short h = f2bf(v);
          unsigned short l = f2bf(v - bf2f(h));
          ((unsigned short*)C)[t] = h;
          ((unsigned short*)C)[t + cLo] = l;
        }
      }
    }
  }
}

// ---------------------------------------------------------------------------
// Pipelined GEMM: 512 threads / 8 waves, BK=32, DEPTH-deep LDS ring (DEPTH=2
// ping-pong -> 64 KB SPLIT / 32 KB nonsplit -> 2-4 blocks/CU for TLP).
// Per K-step: issue stage(kt+1) FIRST (loads in flight under ds_read+MFMA of
// kt), then ONE s_waitcnt vmcnt + ONE s_barrier. Fragment-order LDS
// (conflict-free), global_load_lds width=16, setprio around MFMA cluster.
// Wave grid 2M x 4N: per-wave tile 64 x 32.
// OUTM: 1 = bf16 store, 4 = gh-epilogue, 8 = f32 partial store (split-K via
//       blockIdx.z: K-offset zb*kIters*32, C-offset zb*sC2).
// RESM: 0 = none, 2 = bf16 residual at Rz[m*ldr+n].
// ---------------------------------------------------------------------------
template<int BM, int BN, bool SPLIT, int OUTM, int RESM, int DEPTH>
__global__ __launch_bounds__(512, 2)
void k_gemm2(const unsigned short* __restrict__ A, long lda, long aLo,
             const unsigned short* __restrict__ B, long ldb, long bLo,
             void* __restrict__ C, long ldc, long sC2,
             const void* __restrict__ Rz, long ldr,
             const unsigned short* __restrict__ G1p, const float* __restrict__ ewp, int slot,
             int kIters)
{
  constexpr int ASZ = BM * 32 * (SPLIT ? 2 : 1);
  constexpr int BSZ = BN * 32 * (SPLIT ? 2 : 1);
  constexpr int TSZ = ASZ + BSZ;
  constexpr int FM = BM / 32, FN = BN / 64;     // per-wave frag counts
  constexpr int LPT = (SPLIT ? 2 : 1) * (BM / 128 + BN / 128);  // loads/thread/tile
  static_assert(LPT >= 2 && LPT <= 4, "vmcnt constants assume LPT in {2,3,4}");
  __shared__ __attribute__((aligned(16))) unsigned short sm[DEPTH * TSZ];

  const int tid = threadIdx.x;
  const int w = tid >> 6, lane = tid & 63;
  const int wm = (w >> 2) * (BM / 2), wn = (w & 3) * (BN / 4);
  const int zb = blockIdx.z;
  const long k0 = (OUTM == 8) ? (long)zb * (long)kIters * 32 : 0;
  const unsigned short* Ab = A + (long)blockIdx.x * BM * lda + k0;
  const unsigned short* Bb = B + (long)blockIdx.y * BN * ldb + k0;
  const int rA = lane & 15;
  const int cc = (lane >> 4) * 8;

  floatx4 acc[FM][FN];
  floatx4 zv = {0.f, 0.f, 0.f, 0.f};
#pragma unroll
  for (int i = 0; i < FM; ++i)
#pragma unroll
    for (int j = 0; j < FN; ++j) acc[i][j] = zv;

  // stage tile kt into ring slot kt%DEPTH (fragment order; wave-uniform LDS base)
  auto stage = [&](int kt) {
    const unsigned short* pa = Ab + (long)kt * 32;
    const unsigned short* pb = Bb + (long)kt * 32;
    unsigned short* sa = sm + (size_t)(kt & (DEPTH - 1)) * TSZ;
    unsigned short* sb = sa + ASZ;
#pragma unroll
    for (int r = 0; r < BM / 128; ++r) {
      const int b = r * 8 + w;
      const long row = b * 16 + rA;
      GLOAD16(pa + row * lda + cc, sa + b * 512);
      if (SPLIT) GLOAD16(pa + aLo + row * lda + cc, sa + BM * 32 + b * 512);
    }
#pragma unroll
    for (int r = 0; r < BN / 128; ++r) {
      const int b = r * 8 + w;
      const long row = b * 16 + rA;
      GLOAD16(pb + row * ldb + cc, sb + b * 512);
      if (SPLIT) GLOAD16(pb + bLo + row * ldb + cc, sb + BN * 32 + b * 512);
    }
  };

  // counted pipeline wait: 'ahead' = tiles allowed to remain in flight
  auto waitpipe = [&](int ahead) {
    if (DEPTH == 2) { WAITVM(0); return; }
    if (LPT == 4) {
      if (ahead >= 2) { WAITVM(8); }
      else if (ahead == 1) { WAITVM(4); }
      else { WAITVM(0); }
    } else if (LPT == 3) {
      if (ahead >= 2) { WAITVM(6); }
      else if (ahead == 1) { WAITVM(3); }
      else { WAITVM(0); }
    } else {
      if (ahead >= 2) { WAITVM(4); }
      else if (ahead == 1) { WAITVM(2); }
      else { WAITVM(0); }
    }
  };

  // prologue: stage DEPTH-1 tiles ahead, wait for tile 0 only
  {
    int np = DEPTH - 1; if (np > kIters) np = kIters;
    for (int p = 0; p < np; ++p) stage(p);
    __builtin_amdgcn_sched_barrier(0);
    waitpipe(np - 1);
    __builtin_amdgcn_s_barrier();
  }

  const int aoff = (wm >> 4) * 512 + lane * 8;
  const int boff = (wn >> 4) * 512 + lane * 8;

  for (int kt = 0; kt < kIters; ++kt) {
    if (kt + DEPTH - 1 < kIters) stage(kt + DEPTH - 1);

    const unsigned short* sa = sm + (size_t)(kt & (DEPTH - 1)) * TSZ;
    const unsigned short* sb = sa + ASZ;
    bf16x8 af[FM], bfr[FN];
#pragma unroll
    for (int i = 0; i < FM; ++i)
      af[i] = *(const bf16x8*)(sa + aoff + i * 512);
#pragma unroll
    for (int j = 0; j < FN; ++j)
      bfr[j] = *(const bf16x8*)(sb + boff + j * 512);
    if (SPLIT) {
      bf16x8 al[FM], bl[FN];
#pragma unroll
      for (int i = 0; i < FM; ++i)
        al[i] = *(const bf16x8*)(sa + BM * 32 + aoff + i * 512);
#pragma unroll
      for (int j = 0; j < FN; ++j)
        bl[j] = *(const bf16x8*)(sb + BN * 32 + boff + j * 512);
      __builtin_amdgcn_s_setprio(1);
#pragma unroll
      for (int i = 0; i < FM; ++i)
#pragma unroll
        for (int j = 0; j < FN; ++j) {
          acc[i][j] = __builtin_amdgcn_mfma_f32_16x16x32_bf16(af[i], bfr[j], acc[i][j], 0, 0, 0);
          acc[i][j] = __builtin_amdgcn_mfma_f32_16x16x32_bf16(af[i], bl[j], acc[i][j], 0, 0, 0);
          acc[i][j] = __builtin_amdgcn_mfma_f32_16x16x32_bf16(al[i], bfr[j], acc[i][j], 0, 0, 0);
        }
      __builtin_amdgcn_s_setprio(0);
    } else {
      __builtin_amdgcn_s_setprio(1);
#pragma unroll
      for (int i = 0; i < FM; ++i)
#pragma unroll
        for (int j = 0; j < FN; ++j)
          acc[i][j] = __builtin_amdgcn_mfma_f32_16x16x32_bf16(af[i], bfr[j], acc[i][j], 0, 0, 0);
      __builtin_amdgcn_s_setprio(0);
    }

    __builtin_amdgcn_sched_barrier(0);
    int ahead = kIters - 2 - kt;
    if (ahead > DEPTH - 2) ahead = DEPTH - 2;
    if (ahead < 0) ahead = 0;
    waitpipe(ahead);
    __builtin_amdgcn_s_barrier();
  }

  const long mb = (long)blockIdx.x * BM + wm + ((lane >> 4) * 4);
  const long nb = (long)blockIdx.y * BN + wn + (lane & 15);
  const long cbase = (long)zb * sC2;
#pragma unroll
  for (int i = 0; i < FM; ++i) {
#pragma unroll
    for (int j = 0; j < FN; ++j) {
#pragma unroll
      for (int rr = 0; rr < 4; ++rr) {
        long m = mb + i * 16 + rr;
        long n = nb + j * 16;
        float v = acc[i][j][rr];
        if (RESM == 2) v += bf2f(((const unsigned short*)Rz)[m * ldr + n]);
        if (OUTM == 8) ((float*)C)[cbase + m * ldc + n] = v;
        else if (OUTM == 4) {
          float g1 = bf2f(G1p[m * ldc + n]);
          float s1 = g1 / (1.f + __expf(-g1));
          ((unsigned short*)C)[m * ldc + n] = f2bf(ewp[m * 2 + slot] * s1 * v);
        }
        else ((unsigned short*)C)[m * ldc + n] = f2bf(v);
      }
    }
  }
}

// ---------------------------------------------------------------------------
__global__ void k_rmsnorm(const float* __restrict__ x, const float* __restrict__ w,
                          unsigned short* __restrict__ ob, long loOff){
  int t = blockIdx.x;
  const float* row = x + (size_t)t * 2048;
  float ss = 0.f;
  for (int i = threadIdx.x; i < 2048; i += 256){ float v = row[i]; ss += v * v; }
#pragma unroll
  for (int o = 32; o; o >>= 1) ss += __shfl_xor(ss, o);
  __shared__ float sred[4]; __shared__ float srms;
  int lane = threadIdx.x & 63, wid = threadIdx.x >> 6;
  if (lane == 0) sred[wid] = ss;
  __syncthreads();
  if (threadIdx.x == 0) srms = rsqrtf((sred[0]+sred[1]+sred[2]+sred[3]) * (1.f/2048.f) + 1e-5f);
  __syncthreads();
  float rr = srms;
  for (int i = threadIdx.x; i < 2048; i += 256){
    float v = row[i] * rr * w[i];
    unsigned short h = f2bf(v);
    ob[(size_t)t * 2048 + i] = h;
    if (loOff) ob[(size_t)t * 2048 + i + loOff] = f2bf(v - bf2f(h));
  }
}

// out[n][k] = pair(W[n][k] + 2*sum_r Bm[n][r]*A[r][k]);  K fixed = 2048
__global__ void k_fold(const float* __restrict__ W, const float* __restrict__ Bm,
                       const float* __restrict__ A, unsigned short* __restrict__ out, long loOff){
  int idx = blockIdx.x * 256 + threadIdx.x;
  int n = idx >> 11, k = idx & 2047;
  float acc = W[idx];
  const float* br = Bm + (size_t)n * 16;
#pragma unroll
  for (int r = 0; r < 16; ++r) acc += 2.0f * br[r] * A[r * 2048 + k];
  unsigned short h = f2bf(acc);
  out[idx] = h;
  out[idx + loOff] = f2bf(acc - bf2f(h));
}

__global__ void k_cvt4(const float* __restrict__ in, unsigned short* __restrict__ out){
  int i = (blockIdx.x * 256 + threadIdx.x) * 4;
  float4 v = *(const float4*)(in + i);
  unsigned long long pk = (unsigned long long)f2bf(v.x)
    | ((unsigned long long)f2bf(v.y) << 16)
    | ((unsigned long long)f2bf(v.z) << 32)
    | ((unsigned long long)f2bf(v.w) << 48);
  *(unsigned long long*)(out + i) = pk;
}

// eB [E][F][16] -> out [F][128] with out[f][e*16+r] = eB[e][f][r]
__global__ void k_beff(const float* __restrict__ eB, unsigned short* __restrict__ out, int F){
  int idx = blockIdx.x * 256 + threadIdx.x;
  int f = idx >> 7, er = idx & 127;
  int e = er >> 4, r = er & 15;
  out[idx] = f2bf(eB[((size_t)e * F + f) * 16 + r]);
}

// fused QKV epilogue: sum split-K partials, rope (q,k), pairize, V-transpose
// P: [2][2048][3072] f32. One thread per column-pair.
__global__ void k_qkv_epi(const float* __restrict__ P,
                          const float* __restrict__ rc, const float* __restrict__ rs,
                          unsigned short* __restrict__ qb, unsigned short* __restrict__ kb,
                          unsigned short* __restrict__ vT){
  int idx = blockIdx.x * 256 + threadIdx.x;   // 0 .. 2048*1536-1
  int t = idx / 1536, p = idx - t * 1536;
  int c = p * 2;
  const float2 a = *(const float2*)(P + (size_t)t * 3072 + c);
  const float2 b = *(const float2*)(P + 6291456 + (size_t)t * 3072 + c);
  float v0 = a.x + b.x, v1 = a.y + b.y;
  int s = t & 511;
  if (c < 2560) {
    int i = (c & 127) >> 1;
    float co = rc[s * 64 + i], sn = rs[s * 64 + i];
    float o0 = v0 * co - v1 * sn;
    float o1 = v0 * sn + v1 * co;
    v0 = o0; v1 = o1;
  }
  unsigned short h0 = f2bf(v0), l0 = f2bf(v0 - bf2f(h0));
  unsigned short h1 = f2bf(v1), l1 = f2bf(v1 - bf2f(h1));
  if (c < 2048) {
    size_t o = (size_t)t * 2048 + c;
    qb[o] = h0; qb[o + 1] = h1;
    qb[o + 4194304] = l0; qb[o + 4194305] = l1;
  } else if (c < 2560) {
    size_t o = (size_t)t * 512 + (c - 2048);
    kb[o] = h0; kb[o + 1] = h1;
    kb[o + 1048576] = l0; kb[o + 1048577] = l1;
  } else {
    int d = c - 2560;
    int kv = d >> 7, dI = d & 127, bq = t >> 9;
    size_t o = (((size_t)(bq * 4 + kv) * 128 + dI) << 9) + s;
    vT[o] = h0; vT[o + 512] = h1;
    vT[o + 1048576] = l0; vT[o + 1048576 + 512] = l1;
  }
}

// out = P0 + P1 + res (f32, float4); works in-place when res==out
__global__ void k_add2res(const float* __restrict__ P, const float* __restrict__ res,
                          float* __restrict__ out){
  int i = (blockIdx.x * 256 + threadIdx.x) * 4;
  float4 a = *(const float4*)(P + i);
  float4 b = *(const float4*)(P + 4194304 + i);
  float4 r = *(const float4*)(res + i);
  float4 o; o.x = a.x + b.x + r.x; o.y = a.y + b.y + r.y;
  o.z = a.z + b.z + r.z; o.w = a.w + b.w + r.w;
  *(float4*)(out + i) = o;
}

// f32 causal softmax, in-place repack to P hi/lo halves per 1024-ushort row
__global__ void k_softmax(float* __restrict__ sp){
  int row = blockIdx.x;
  int s = row & 511;
  float* in = sp + (size_t)row * 512;
  unsigned short* op = (unsigned short*)in;
  int t0 = threadIdx.x, t1 = threadIdx.x + 256;
  const float scale = 0.088388347648318447f;
  float v0 = (t0 <= s) ? in[t0] * scale : -3.0e38f;
  float v1 = (t1 <= s) ? in[t1] * scale : -3.0e38f;
  float mx = fmaxf(v0, v1);
#pragma unroll
  for (int o = 32; o; o >>= 1) mx = fmaxf(mx, __shfl_xor(mx, o));
  __shared__ float sred[8];
  int lane = threadIdx.x & 63, wid = threadIdx.x >> 6;
  if (lane == 0) sred[wid] = mx;
  __syncthreads();
  mx = fmaxf(fmaxf(sred[0], sred[1]), fmaxf(sred[2], sred[3]));
  float e0 = (t0 <= s) ? __expf(v0 - mx) : 0.f;
  float e1 = (t1 <= s) ? __expf(v1 - mx) : 0.f;
  float sum = e0 + e1;
#pragma unroll
  for (int o = 32; o; o >>= 1) sum += __shfl_xor(sum, o);
  if (lane == 0) sred[4 + wid] = sum;
  __syncthreads();
  sum = sred[4] + sred[5] + sred[6] + sred[7];
  float inv = 1.f / sum;
  float p0 = e0 * inv, p1 = e1 * inv;
  unsigned short h0 = f2bf(p0), h1 = f2bf(p1);
  op[t0] = h0; op[512 + t0] = f2bf(p0 - bf2f(h0));
  op[t1] = h1; op[512 + t1] = f2bf(p1 - bf2f(h1));
}

// exact-f32 routing
__global__ void k_route(const float* __restrict__ x2, const float* __restrict__ w,
                        const float* __restrict__ gw, int* __restrict__ eidx,
                        float* __restrict__ ew){
  int t = blockIdx.x; int lane = threadIdx.x;
  const float* row = x2 + (size_t)t * 2048;
  float ss = 0.f;
  for (int d = lane; d < 2048; d += 64){ float v = row[d]; ss += v * v; }
#pragma unroll
  for (int o = 32; o; o >>= 1) ss += __shfl_xor(ss, o);
  float rr = rsqrtf(ss * (1.f/2048.f) + 1e-5f);
  float acc[8] = {0,0,0,0,0,0,0,0};
  for (int d = lane; d < 2048; d += 64){
    float xv = row[d] * rr * w[d];
#pragma unroll
    for (int e = 0; e < 8; ++e) acc[e] += xv * gw[e * 2048 + d];
  }
#pragma unroll
  for (int e = 0; e < 8; ++e)
#pragma unroll
    for (int o = 32; o; o >>= 1) acc[e] += __shfl_xor(acc[e], o);
  if (lane == 0){
    int i0 = 0;
#pragma unroll
    for (int e = 1; e < 8; ++e) if (acc[e] > acc[i0]) i0 = e;
    int i1 = -1;
#pragma unroll
    for (int e = 0; e < 8; ++e) if (e != i0 && (i1 < 0 || acc[e] > acc[i1])) i1 = e;
    float p1 = __expf(acc[i1] - acc[i0]);
    float inv = 1.f / (1.f + p1);
    eidx[t * 2 + 0] = i0; eidx[t * 2 + 1] = i1;
    ew[t * 2 + 0] = inv;  ew[t * 2 + 1] = p1 * inv;
  }
}

__global__ void k_zero(float* __restrict__ p){
  p[(size_t)blockIdx.x * 256 + threadIdx.x] = 0.f;
}

__global__ void k_ubuild(const float* __restrict__ U1, const float* __restrict__ U3,
                         const int* __restrict__ eidx,
                         unsigned short* __restrict__ u10, unsigned short* __restrict__ u11,
                         unsigned short* __restrict__ u30, unsigned short* __restrict__ u31){
  int idx = blockIdx.x * 256 + threadIdx.x;
  int t = idx >> 7, j = idx & 127; int e = j >> 4;
  int e0 = eidx[t * 2], e1 = eidx[t * 2 + 1];
  float v1 = U1[idx] * 2.0f, v3 = U3[idx] * 2.0f;
  u10[idx] = (e == e0) ? f2bf(v1) : (unsigned short)0;
  u11[idx] = (e == e1) ? f2bf(v1) : (unsigned short)0;
  u30[idx] = (e == e0) ? f2bf(v3) : (unsigned short)0;
  u31[idx] = (e == e1) ? f2bf(v3) : (unsigned short)0;
}

__global__ void k_addip(unsigned short* __restrict__ a, const unsigned short* __restrict__ b){
  size_t i = (size_t)blockIdx.x * 256 + threadIdx.x;
  a[i] = f2bf(bf2f(a[i]) + bf2f(b[i]));
}

__global__ void k_vhat(const float* __restrict__ U20, const float* __restrict__ U21,
                       const int* __restrict__ eidx, unsigned short* __restrict__ out){
  int idx = blockIdx.x * 256 + threadIdx.x;
  int t = idx >> 7, j = idx & 127; int e = j >> 4;
  int e0 = eidx[t * 2], e1 = eidx[t * 2 + 1];
  float v = 0.f;
  if (e == e0) v = 2.0f * U20[idx];
  else if (e == e1) v = 2.0f * U21[idx];
  out[idx] = f2bf(v);
}

// ---------------------------------------------------------------------------
extern "C" void kernel_launch(void* const* d_in, const int* in_sizes, int n_in,
                              void* d_out, int out_size, void* d_ws, size_t ws_size,
                              hipStream_t stream){
  const float* data  = (const float*)d_in[0];
  const float* rcos  = (const float*)d_in[2];
  const float* rsin  = (const float*)d_in[3];
  const float* attw  = (const float*)d_in[4];
  const float* ffnw  = (const float*)d_in[5];
  const float* wq    = (const float*)d_in[6];
  const float* wk    = (const float*)d_in[7];
  const float* wv    = (const float*)d_in[8];
  const float* wo    = (const float*)d_in[9];
  const float* lqA   = (const float*)d_in[10];
  const float* lqB   = (const float*)d_in[11];
  const float* lkA   = (const float*)d_in[12];
  const float* lkB   = (const float*)d_in[13];
  const float* lvA   = (const float*)d_in[14];
  const float* lvB   = (const float*)d_in[15];
  const float* loA   = (const float*)d_in[16];
  const float* loB   = (const float*)d_in[17];
  const float* w1    = (const float*)d_in[18];
  const float* w2    = (const float*)d_in[19];
  const float* w3    = (const float*)d_in[20];
  const float* gatew = (const float*)d_in[21];
  const float* eA1   = (const float*)d_in[22];
  const float* eB1   = (const float*)d_in[23];
  const float* eA2   = (const float*)d_in[24];
  const float* eB2   = (const float*)d_in[25];
  const float* eA3   = (const float*)d_in[26];
  const float* eB3   = (const float*)d_in[27];
  (void)in_sizes; (void)n_in; (void)out_size; (void)ws_size;

  char* base = (char*)d_ws;
  float* data2 = (float*)d_out;  // residual stream f32 [2048][2048]

  // ---- attention arena (phase-overlaid byte offsets) ----
  unsigned short* hb   = (unsigned short*)(base + 0);         // pair 16.8 MB
  unsigned short* Wqkv = (unsigned short*)(base + 16777216);  // pair [3072][2048] 25.2 MB
  float*          QKVf = (float*)(base + 41943040);           // [2][2048][3072] 50.3 MB -> end 92.3 MB
  unsigned short* qb   = (unsigned short*)(base + 92274688);  // pair 16.8 MB
  unsigned short* kb   = (unsigned short*)(base + 109051904); // pair 4.2 MB
  unsigned short* vT   = (unsigned short*)(base + 113246208); // pair 4.2 MB -> end 117.4 MB
  float*          sc   = (float*)(base + 0);                  // 67.1 MB (after QKV epi)
  unsigned short* scU  = (unsigned short*)(base + 0);
  unsigned short* ao   = (unsigned short*)(base + 67108864);  // pair 16.8 MB (over dead QKVf tail)
  unsigned short* Wo   = (unsigned short*)(base + 0);         // pair 16.8 MB (after PV)
  float*          Wof  = (float*)(base + 16777216);           // [2][2048][2048] 33.6 MB

  // ---- FFN arena (attention fully dead) ----
  size_t off = 0;
  auto alloc = [&](size_t n)->char*{ char* p = base + off; off = (off + n + 255) & ~(size_t)255; return p; };
  int*   eidx = (int*)alloc(16384);
  float* ew   = (float*)alloc(16384);
  unsigned short* hnb  = (unsigned short*)alloc(8388608);
  unsigned short* h1b  = (unsigned short*)alloc(23068672);   // later gh1, later W2f
  unsigned short* h3b  = (unsigned short*)alloc(23068672);
  unsigned short* wbuf = (unsigned short*)alloc(23068672);   // w1 -> w3 -> G1 -> w2
  unsigned short* gh0  = (unsigned short*)alloc(23068672);
  unsigned short* eA1c = (unsigned short*)alloc(524288);
  unsigned short* eA3c = (unsigned short*)alloc(524288);
  unsigned short* eA2c = (unsigned short*)alloc(1441792);
  unsigned short* Bf1  = (unsigned short*)alloc(1441792);
  unsigned short* Bf3  = (unsigned short*)alloc(1441792);
  unsigned short* Bf2  = (unsigned short*)alloc(524288);
  float* Uz = (float*)alloc(4194304);
  float* U1 = Uz, *U3 = Uz + 262144, *U20 = Uz + 524288, *U21 = Uz + 786432;
  unsigned short* Ut10 = (unsigned short*)alloc(524288);
  unsigned short* Ut11 = (unsigned short*)alloc(524288);
  unsigned short* Ut30 = (unsigned short*)alloc(524288);
  unsigned short* Ut31 = (unsigned short*)alloc(524288);
  unsigned short* vhat = (unsigned short*)alloc(524288);
  unsigned short* gh1  = h1b;
  float*          W2f  = (float*)h1b;  // 33.6 MB over h1b+h3b (both dead by then)

  // ================= attention (split hi/lo ~ fp32) =================
  k_rmsnorm<<<2048, 256, 0, stream>>>(data, attw, hb, 4194304);
  k_fold<<<16384, 256, 0, stream>>>(wq, lqB, lqA, Wqkv, 6291456);
  k_fold<<<4096, 256, 0, stream>>>(wk, lkB, lkA, Wqkv + 4194304, 6291456);
  k_fold<<<4096, 256, 0, stream>>>(wv, lvB, lvA, Wqkv + 5242880, 6291456);

  // fused QKV, split-K2 -> f32 partials (pipelined split gemm, 2 blocks/CU)
  k_gemm2<128,128,true,8,0,2><<<dim3(16,24,2), 512, 0, stream>>>(
      hb, 2048, 4194304, Wqkv, 2048, 6291456, QKVf, 3072, 6291456,
      nullptr, 0, nullptr, nullptr, 0, 32);
  k_qkv_epi<<<12288, 256, 0, stream>>>(QKVf, rcos, rsin, qb, kb, vT);

  k_gemm<0,0,true,true><<<dim3(4,4,64), 256, 0, stream>>>(
      qb, 2048, 128, 1048576, 4194304, kb, 512, 128, 262144, 1048576,
      sc, 512, 262144, 4194304, 0, nullptr,0, nullptr,nullptr,0, 4, 4, 2);
  k_softmax<<<32768, 256, 0, stream>>>(sc);
  k_gemm<5,0,false,true><<<dim3(4,1,64), 256, 0, stream>>>(
      scU, 1024, 524288, 8388608, 512, vT, 512, 65536, 262144, 1048576,
      ao, 2048, 128, 1048576, 4194304, nullptr,0, nullptr,nullptr,0, 16, 4, 2);

  k_fold<<<16384, 256, 0, stream>>>(wo, loB, loA, Wo, 4194304);  // sc dead now
  k_gemm2<128,128,true,8,0,2><<<dim3(16,16,2), 512, 0, stream>>>(
      ao, 2048, 4194304, Wo, 2048, 4194304, Wof, 2048, 4194304,
      nullptr, 0, nullptr, nullptr, 0, 32);
  k_add2res<<<4096, 256, 0, stream>>>(Wof, data, data2);

  // ================= FFN (bf16) =================
  k_rmsnorm<<<2048, 256, 0, stream>>>(data2, ffnw, hnb, 0);
  k_route<<<2048, 64, 0, stream>>>(data2, ffnw, gatew, eidx, ew);

  k_cvt4<<<11264, 256, 0, stream>>>(w1, wbuf);
  k_gemm2<128,128,false,1,0,2><<<dim3(16,44,1), 512, 0, stream>>>(
      hnb, 2048, 0, wbuf, 2048, 0, h1b, 5632, 0,
      nullptr, 0, nullptr, nullptr, 0, 64);
  k_cvt4<<<11264, 256, 0, stream>>>(w3, wbuf);
  k_gemm2<128,128,false,1,0,2><<<dim3(16,44,1), 512, 0, stream>>>(
      hnb, 2048, 0, wbuf, 2048, 0, h3b, 5632, 0,
      nullptr, 0, nullptr, nullptr, 0, 64);

  k_cvt4<<<256, 256, 0, stream>>>(eA1, eA1c);
  k_cvt4<<<256, 256, 0, stream>>>(eA3, eA3c);
  k_cvt4<<<704, 256, 0, stream>>>(eA2, eA2c);
  k_beff<<<2816, 256, 0, stream>>>(eB1, Bf1, 5632);
  k_beff<<<2816, 256, 0, stream>>>(eB3, Bf3, 5632);
  k_beff<<<1024, 256, 0, stream>>>(eB2, Bf2, 2048);
  k_zero<<<4096, 256, 0, stream>>>(Uz);

  k_gemm<2,0,false,false><<<dim3(16,1,8), 256, 0, stream>>>(
      hnb,2048,0,0,0, eA1c,2048,0,0,0, U1,128,0,0,0, nullptr,0, nullptr,nullptr,0, 8,0,0);
  k_gemm<2,0,false,false><<<dim3(16,1,8), 256, 0, stream>>>(
      hnb,2048,0,0,0, eA3c,2048,0,0,0, U3,128,0,0,0, nullptr,0, nullptr,nullptr,0, 8,0,0);
  k_ubuild<<<1024, 256, 0, stream>>>(U1, U3, eidx, Ut10, Ut11, Ut30, Ut31);

  // slot 0
  k_gemm2<128,128,false,1,2,2><<<dim3(16,44,1), 512, 0, stream>>>(
      Ut10, 128, 0, Bf1, 128, 0, wbuf, 5632, 0,
      h1b, 5632, nullptr, nullptr, 0, 4);
  k_gemm2<128,128,false,4,2,2><<<dim3(16,44,1), 512, 0, stream>>>(
      Ut30, 128, 0, Bf3, 128, 0, gh0, 5632, 0,
      h3b, 5632, wbuf, ew, 0, 4);
  k_gemm<2,0,false,false><<<dim3(16,1,8), 256, 0, stream>>>(
      gh0,5632,0,0,0, eA2c,5632,0,0,0, U20,128,0,0,0, nullptr,0, nullptr,nullptr,0, 22,0,0);
  // slot 1
  k_gemm2<128,128,false,1,2,2><<<dim3(16,44,1), 512, 0, stream>>>(
      Ut11, 128, 0, Bf1, 128, 0, wbuf, 5632, 0,
      h1b, 5632, nullptr, nullptr, 0, 4);
  k_gemm2<128,128,false,4,2,2><<<dim3(16,44,1), 512, 0, stream>>>(
      Ut31, 128, 0, Bf3, 128, 0, gh1, 5632, 0,
      h3b, 5632, wbuf, ew, 1, 4);
  k_gemm<2,0,false,false><<<dim3(16,1,8), 256, 0, stream>>>(
      gh1,5632,0,0,0, eA2c,5632,0,0,0, U21,128,0,0,0, nullptr,0, nullptr,nullptr,0, 22,0,0);

  k_addip<<<45056, 256, 0, stream>>>(gh0, gh1);
  k_vhat<<<1024, 256, 0, stream>>>(U20, U21, eidx, vhat);
  k_gemm<2,0,false,false><<<dim3(16,16,1), 256, 0, stream>>>(
      vhat,128,0,0,0, Bf2,128,0,0,0, data2,2048,0,0,0, nullptr,0, nullptr,nullptr,0, 4,0,0);
  k_cvt4<<<11264, 256, 0, stream>>>(w2, wbuf);
  k_gemm2<128,128,false,8,0,2><<<dim3(16,16,2), 512, 0, stream>>>(
      gh0, 5632, 0, wbuf, 5632, 0, W2f, 2048, 4194304,
      nullptr, 0, nullptr, nullptr, 0, 88);
  k_add2res<<<4096, 256, 0, stream>>>(W2f, data2, data2);
}

// Round 3
// 1083.679 us; speedup vs baseline: 1.0422x; 1.0422x over previous
//
#include <hip/hip_runtime.h>
#include <stdint.h>

#define DI static __device__ __forceinline__

typedef __attribute__((ext_vector_type(8))) short bf16x8;
typedef __attribute__((ext_vector_type(4))) float floatx4;

DI unsigned short f2bf(float x){
  unsigned int u = __float_as_uint(x);
  u += 0x7fffu + ((u >> 16) & 1u);
  return (unsigned short)(u >> 16);
}
DI float bf2f(unsigned short h){ return __uint_as_float(((unsigned int)h) << 16); }

#define GLOAD16(gp, lp) \
  __builtin_amdgcn_global_load_lds((const __attribute__((address_space(1))) unsigned int*)(gp), \
                                   (__attribute__((address_space(3))) unsigned int*)(lp), 16, 0, 0)

#define WAITVM0 asm volatile("s_waitcnt vmcnt(0)" ::: "memory")

// ---------------------------------------------------------------------------
// bf16 MFMA GEMM: C[M,N] = A[M,K] @ B[N,K]^T (+res), 128x128 tile, BK=32.
// LDS is kept in MFMA-fragment order: staging lane j loads global
// (row=j&15, kchunk=j>>4); fragment read = block*512 + lane*8 -> conflict-free.
// SPLIT: A,B are hi/lo bf16 pairs (lo at +aLo/+bLo elems): 3-pass MFMA ~fp32.
// OUTM: 0=f32 store, 1=bf16 store, 2=f32 atomicAdd (split-K via zb),
//       4=bf16 gh-epilogue (ew*silu(G1)*(acc+res)),
//       5=bf16 hi/lo pair store (+cLo), 6=pair store w/ V-transpose,
//       8=f32 partial store (split-K via zb, partial at zb*sC2)
// RESM: 0=none, 1=f32 residual, 2=bf16 residual (index m*ldr+n)
// CSKIP: skip tiles with blockIdx.y > blockIdx.x (causal)
// batching: zr=z&((1<<zshift)-1), zb=z>>zshift
// ---------------------------------------------------------------------------
template<int OUTM, int RESM, bool CSKIP, bool SPLIT>
__global__ __launch_bounds__(256, 2)
void k_gemm(const unsigned short* __restrict__ A, long lda, long sA1, long sA2, long aLo,
            const unsigned short* __restrict__ B, long ldb, long sB1, long sB2, long bLo,
            void* __restrict__ C, long ldc, long sC1, long sC2, long cLo,
            const void* __restrict__ Rz, long ldr,
            const unsigned short* __restrict__ G1p, const float* __restrict__ ewp, int slot,
            int kIters, int zshift, int bshift)
{
  if (CSKIP && blockIdx.y > blockIdx.x) return;
  __shared__ __attribute__((aligned(16))) unsigned short As[SPLIT ? 8192 : 4096];
  __shared__ __attribute__((aligned(16))) unsigned short Bs[SPLIT ? 8192 : 4096];
  const int tid = threadIdx.x;
  const int w = tid >> 6, lane = tid & 63;
  const int wm = (w >> 1) * 64, wn = (w & 1) * 64;
  const int z = blockIdx.z;
  const int zr = z & ((1 << zshift) - 1);
  const int zb = z >> zshift;
  long k0 = 0;
  if (OUTM == 2 || OUTM == 8) k0 = (long)zb * (long)kIters * 32;
  const unsigned short* Ab = A + (long)((OUTM==8)?0:zb) * sA2 + (long)zr * sA1 + (long)blockIdx.x * 128 * lda + k0;
  const unsigned short* Bb = B + (long)((OUTM==8)?0:zb) * sB2 + (long)(zr >> bshift) * sB1 + (long)blockIdx.y * 128 * ldb + k0;

  // fragment-order staging: lane j -> (row j&15, kchunk j>>4)
  const int rlo = w * 16 + (lane & 15);
  const int rhi = 64 + rlo;
  const int cc  = (lane >> 4) * 8;
  unsigned short* ldsA0 = As + w * 512;
  unsigned short* ldsA1 = As + 2048 + w * 512;
  unsigned short* ldsB0 = Bs + w * 512;
  unsigned short* ldsB1 = Bs + 2048 + w * 512;

  floatx4 acc[4][4];
  floatx4 zv = {0.f, 0.f, 0.f, 0.f};
#pragma unroll
  for (int i = 0; i < 4; ++i)
#pragma unroll
    for (int j = 0; j < 4; ++j) acc[i][j] = zv;

  const int abase = (wm >> 4) * 512 + lane * 8;
  const int bbase = (wn >> 4) * 512 + lane * 8;

  for (int kt = 0; kt < kIters; ++kt) {
    const unsigned short* pa = Ab + (long)kt * 32;
    const unsigned short* pb = Bb + (long)kt * 32;
    GLOAD16(pa + (long)rlo * lda + cc, ldsA0);
    GLOAD16(pa + (long)rhi * lda + cc, ldsA1);
    GLOAD16(pb + (long)rlo * ldb + cc, ldsB0);
    GLOAD16(pb + (long)rhi * ldb + cc, ldsB1);
    if (SPLIT) {
      const unsigned short* pal = pa + aLo;
      const unsigned short* pbl = pb + bLo;
      GLOAD16(pal + (long)rlo * lda + cc, As + 4096 + w * 512);
      GLOAD16(pal + (long)rhi * lda + cc, As + 6144 + w * 512);
      GLOAD16(pbl + (long)rlo * ldb + cc, Bs + 4096 + w * 512);
      GLOAD16(pbl + (long)rhi * ldb + cc, Bs + 6144 + w * 512);
    }
    __syncthreads();
    bf16x8 af[4], bfr[4];
#pragma unroll
    for (int i = 0; i < 4; ++i)
      af[i] = *(const bf16x8*)(As + abase + i * 512);
#pragma unroll
    for (int j = 0; j < 4; ++j)
      bfr[j] = *(const bf16x8*)(Bs + bbase + j * 512);
    if (SPLIT) {
      bf16x8 al[4], bl[4];
#pragma unroll
      for (int i = 0; i < 4; ++i)
        al[i] = *(const bf16x8*)(As + 4096 + abase + i * 512);
#pragma unroll
      for (int j = 0; j < 4; ++j)
        bl[j] = *(const bf16x8*)(Bs + 4096 + bbase + j * 512);
#pragma unroll
      for (int i = 0; i < 4; ++i)
#pragma unroll
        for (int j = 0; j < 4; ++j) {
          acc[i][j] = __builtin_amdgcn_mfma_f32_16x16x32_bf16(af[i], bfr[j], acc[i][j], 0, 0, 0);
          acc[i][j] = __builtin_amdgcn_mfma_f32_16x16x32_bf16(af[i], bl[j], acc[i][j], 0, 0, 0);
          acc[i][j] = __builtin_amdgcn_mfma_f32_16x16x32_bf16(al[i], bfr[j], acc[i][j], 0, 0, 0);
        }
    } else {
#pragma unroll
      for (int i = 0; i < 4; ++i)
#pragma unroll
        for (int j = 0; j < 4; ++j)
          acc[i][j] = __builtin_amdgcn_mfma_f32_16x16x32_bf16(af[i], bfr[j], acc[i][j], 0, 0, 0);
    }
    __syncthreads();
  }

  const long mb = (long)blockIdx.x * 128 + wm + ((lane >> 4) * 4);
  const long nb = (long)blockIdx.y * 128 + wn + (lane & 15);
  const long cbase = (long)zb * sC2 + (long)zr * sC1;
#pragma unroll
  for (int i = 0; i < 4; ++i) {
#pragma unroll
    for (int j = 0; j < 4; ++j) {
#pragma unroll
      for (int rr = 0; rr < 4; ++rr) {
        long m = mb + i * 16 + rr;
        long n = nb + j * 16;
        float v = acc[i][j][rr];
        if (RESM == 1) v += ((const float*)Rz)[m * ldr + n];
        if (RESM == 2) v += bf2f(((const unsigned short*)Rz)[m * ldr + n]);
        if (OUTM == 0 || OUTM == 8) ((float*)C)[cbase + m * ldc + n] = v;
        else if (OUTM == 1) ((unsigned short*)C)[cbase + m * ldc + n] = f2bf(v);
        else if (OUTM == 2) atomicAdd((float*)C + cbase + m * ldc + n, v);
        else if (OUTM == 4) {
          float g1 = bf2f(G1p[m * ldc + n]);
          float s1 = g1 / (1.f + __expf(-g1));
          ((unsigned short*)C)[cbase + m * ldc + n] = f2bf(ewp[m * 2 + slot] * s1 * v);
        } else if (OUTM == 5) {
          unsigned short h = f2bf(v);
          unsigned short l = f2bf(v - bf2f(h));
          ((unsigned short*)C)[cbase + m * ldc + n] = h;
          ((unsigned short*)C)[cbase + m * ldc + n + cLo] = l;
        } else {  // OUTM == 6
          long bq = m >> 9, sI = m & 511, kv = n >> 7, dI = n & 127;
          long t = (((bq * 4 + kv) * 128 + dI) << 9) + sI;
          unsigned short h = f2bf(v);
          unsigned short l = f2bf(v - bf2f(h));
          ((unsigned short*)C)[t] = h;
          ((unsigned short*)C)[t + cLo] = l;
        }
      }
    }
  }
}

// ---------------------------------------------------------------------------
// Big-tile pipelined GEMM: 512 threads / 8 waves (2M x 4N), BK=32, DEPTH=2
// LDS ping-pong. Tile BM x BN (128/256 each); per-wave (BM/2) x (BN/4).
// Big tiles are the point: operand staging traffic = (N/BN)|A| + (M/BM)|B|,
// and the GEMMs are cache-BW-bound on that traffic (~7 TB/s L2/L3 ceiling).
// Stage(kt+1) issued before compute(kt); one vmcnt drain + one barrier/step.
// Fragment-order LDS (conflict-free), global_load_lds width=16, setprio.
// OUTM: 1 = bf16 store, 8 = f32 partial store (split-K via blockIdx.z:
//       K-offset zb*kIters*32, C-offset zb*sC2).
// ---------------------------------------------------------------------------
template<int BM, int BN, bool SPLIT, int OUTM, int DEPTH>
__global__ __launch_bounds__(512, 2)
void k_gemm2(const unsigned short* __restrict__ A, long lda, long aLo,
             const unsigned short* __restrict__ B, long ldb, long bLo,
             void* __restrict__ C, long ldc, long sC2, int kIters)
{
  constexpr int ASZ = BM * 32 * (SPLIT ? 2 : 1);   // shorts
  constexpr int BSZ = BN * 32 * (SPLIT ? 2 : 1);
  constexpr int TSZ = ASZ + BSZ;
  constexpr int FM = BM / 32, FN = BN / 64;        // per-wave frag counts
  __shared__ __attribute__((aligned(16))) unsigned short sm[DEPTH * TSZ];

  const int tid = threadIdx.x;
  const int w = tid >> 6, lane = tid & 63;
  const int wm = (w >> 2) * (BM / 2), wn = (w & 3) * (BN / 4);
  const int zb = blockIdx.z;
  const long k0 = (OUTM == 8) ? (long)zb * (long)kIters * 32 : 0;
  const unsigned short* Ab = A + (long)blockIdx.x * BM * lda + k0;
  const unsigned short* Bb = B + (long)blockIdx.y * BN * ldb + k0;
  const int rA = lane & 15;
  const int cc = (lane >> 4) * 8;

  floatx4 acc[FM][FN];
  floatx4 zv = {0.f, 0.f, 0.f, 0.f};
#pragma unroll
  for (int i = 0; i < FM; ++i)
#pragma unroll
    for (int j = 0; j < FN; ++j) acc[i][j] = zv;

  // stage tile kt into ring slot kt&1 (fragment order; wave-uniform LDS base)
  auto stage = [&](int kt) {
    const unsigned short* pa = Ab + (long)kt * 32;
    const unsigned short* pb = Bb + (long)kt * 32;
    unsigned short* sa = sm + (size_t)(kt & (DEPTH - 1)) * TSZ;
    unsigned short* sb = sa + ASZ;
#pragma unroll
    for (int r = 0; r < BM / 128; ++r) {
      const int b = r * 8 + w;
      const long row = b * 16 + rA;
      GLOAD16(pa + row * lda + cc, sa + b * 512);
      if (SPLIT) GLOAD16(pa + aLo + row * lda + cc, sa + BM * 32 + b * 512);
    }
#pragma unroll
    for (int r = 0; r < BN / 128; ++r) {
      const int b = r * 8 + w;
      const long row = b * 16 + rA;
      GLOAD16(pb + row * ldb + cc, sb + b * 512);
      if (SPLIT) GLOAD16(pb + bLo + row * ldb + cc, sb + BN * 32 + b * 512);
    }
  };

  // prologue: stage tile 0, wait, barrier
  stage(0);
  __builtin_amdgcn_sched_barrier(0);
  WAITVM0;
  __builtin_amdgcn_s_barrier();

  const int aoff = (wm >> 4) * 512 + lane * 8;
  const int boff = (wn >> 4) * 512 + lane * 8;

  for (int kt = 0; kt < kIters; ++kt) {
    if (kt + 1 < kIters) stage(kt + 1);

    const unsigned short* sa = sm + (size_t)(kt & (DEPTH - 1)) * TSZ;
    const unsigned short* sb = sa + ASZ;
    if (SPLIT) {
      bf16x8 bfr[FN], bl[FN];
#pragma unroll
      for (int j = 0; j < FN; ++j) {
        bfr[j] = *(const bf16x8*)(sb + boff + j * 512);
        bl[j]  = *(const bf16x8*)(sb + BN * 32 + boff + j * 512);
      }
      __builtin_amdgcn_s_setprio(1);
#pragma unroll
      for (int i = 0; i < FM; ++i) {
        bf16x8 ai = *(const bf16x8*)(sa + aoff + i * 512);
        bf16x8 ali = *(const bf16x8*)(sa + BM * 32 + aoff + i * 512);
#pragma unroll
        for (int j = 0; j < FN; ++j) {
          acc[i][j] = __builtin_amdgcn_mfma_f32_16x16x32_bf16(ai, bfr[j], acc[i][j], 0, 0, 0);
          acc[i][j] = __builtin_amdgcn_mfma_f32_16x16x32_bf16(ai, bl[j], acc[i][j], 0, 0, 0);
          acc[i][j] = __builtin_amdgcn_mfma_f32_16x16x32_bf16(ali, bfr[j], acc[i][j], 0, 0, 0);
        }
      }
      __builtin_amdgcn_s_setprio(0);
    } else {
      bf16x8 bfr[FN];
#pragma unroll
      for (int j = 0; j < FN; ++j)
        bfr[j] = *(const bf16x8*)(sb + boff + j * 512);
      __builtin_amdgcn_s_setprio(1);
#pragma unroll
      for (int i = 0; i < FM; ++i) {
        bf16x8 ai = *(const bf16x8*)(sa + aoff + i * 512);
#pragma unroll
        for (int j = 0; j < FN; ++j)
          acc[i][j] = __builtin_amdgcn_mfma_f32_16x16x32_bf16(ai, bfr[j], acc[i][j], 0, 0, 0);
      }
      __builtin_amdgcn_s_setprio(0);
    }

    __builtin_amdgcn_sched_barrier(0);
    WAITVM0;
    __builtin_amdgcn_s_barrier();
  }

  const long mb = (long)blockIdx.x * BM + wm + ((lane >> 4) * 4);
  const long nb = (long)blockIdx.y * BN + wn + (lane & 15);
  const long cbase = (long)zb * sC2;
#pragma unroll
  for (int i = 0; i < FM; ++i) {
#pragma unroll
    for (int j = 0; j < FN; ++j) {
#pragma unroll
      for (int rr = 0; rr < 4; ++rr) {
        long m = mb + i * 16 + rr;
        long n = nb + j * 16;
        float v = acc[i][j][rr];
        if (OUTM == 8) ((float*)C)[cbase + m * ldc + n] = v;
        else ((unsigned short*)C)[m * ldc + n] = f2bf(v);
      }
    }
  }
}

// ---------------------------------------------------------------------------
__global__ void k_rmsnorm(const float* __restrict__ x, const float* __restrict__ w,
                          unsigned short* __restrict__ ob, long loOff){
  int t = blockIdx.x;
  const float* row = x + (size_t)t * 2048;
  float ss = 0.f;
  for (int i = threadIdx.x; i < 2048; i += 256){ float v = row[i]; ss += v * v; }
#pragma unroll
  for (int o = 32; o; o >>= 1) ss += __shfl_xor(ss, o);
  __shared__ float sred[4]; __shared__ float srms;
  int lane = threadIdx.x & 63, wid = threadIdx.x >> 6;
  if (lane == 0) sred[wid] = ss;
  __syncthreads();
  if (threadIdx.x == 0) srms = rsqrtf((sred[0]+sred[1]+sred[2]+sred[3]) * (1.f/2048.f) + 1e-5f);
  __syncthreads();
  float rr = srms;
  for (int i = threadIdx.x; i < 2048; i += 256){
    float v = row[i] * rr * w[i];
    unsigned short h = f2bf(v);
    ob[(size_t)t * 2048 + i] = h;
    if (loOff) ob[(size_t)t * 2048 + i + loOff] = f2bf(v - bf2f(h));
  }
}

// out[n][k] = pair(W[n][k] + 2*sum_r Bm[n][r]*A[r][k]);  K fixed = 2048
__global__ void k_fold(const float* __restrict__ W, const float* __restrict__ Bm,
                       const float* __restrict__ A, unsigned short* __restrict__ out, long loOff){
  int idx = blockIdx.x * 256 + threadIdx.x;
  int n = idx >> 11, k = idx & 2047;
  float acc = W[idx];
  const float* br = Bm + (size_t)n * 16;
#pragma unroll
  for (int r = 0; r < 16; ++r) acc += 2.0f * br[r] * A[r * 2048 + k];
  unsigned short h = f2bf(acc);
  out[idx] = h;
  out[idx + loOff] = f2bf(acc - bf2f(h));
}

__global__ void k_cvt4(const float* __restrict__ in, unsigned short* __restrict__ out){
  int i = (blockIdx.x * 256 + threadIdx.x) * 4;
  float4 v = *(const float4*)(in + i);
  unsigned long long pk = (unsigned long long)f2bf(v.x)
    | ((unsigned long long)f2bf(v.y) << 16)
    | ((unsigned long long)f2bf(v.z) << 32)
    | ((unsigned long long)f2bf(v.w) << 48);
  *(unsigned long long*)(out + i) = pk;
}

// eB [E][F][16] -> out [F][128] with out[f][e*16+r] = eB[e][f][r]
__global__ void k_beff(const float* __restrict__ eB, unsigned short* __restrict__ out, int F){
  int idx = blockIdx.x * 256 + threadIdx.x;
  int f = idx >> 7, er = idx & 127;
  int e = er >> 4, r = er & 15;
  out[idx] = f2bf(eB[((size_t)e * F + f) * 16 + r]);
}

// fused QKV epilogue: sum split-K partials, rope (q,k), pairize, V-transpose
// P: [2][2048][3072] f32. One thread per column-pair.
__global__ void k_qkv_epi(const float* __restrict__ P,
                          const float* __restrict__ rc, const float* __restrict__ rs,
                          unsigned short* __restrict__ qb, unsigned short* __restrict__ kb,
                          unsigned short* __restrict__ vT){
  int idx = blockIdx.x * 256 + threadIdx.x;   // 0 .. 2048*1536-1
  int t = idx / 1536, p = idx - t * 1536;
  int c = p * 2;
  const float2 a = *(const float2*)(P + (size_t)t * 3072 + c);
  const float2 b = *(const float2*)(P + 6291456 + (size_t)t * 3072 + c);
  float v0 = a.x + b.x, v1 = a.y + b.y;
  int s = t & 511;
  if (c < 2560) {
    int i = (c & 127) >> 1;
    float co = rc[s * 64 + i], sn = rs[s * 64 + i];
    float o0 = v0 * co - v1 * sn;
    float o1 = v0 * sn + v1 * co;
    v0 = o0; v1 = o1;
  }
  unsigned short h0 = f2bf(v0), l0 = f2bf(v0 - bf2f(h0));
  unsigned short h1 = f2bf(v1), l1 = f2bf(v1 - bf2f(h1));
  if (c < 2048) {
    size_t o = (size_t)t * 2048 + c;
    qb[o] = h0; qb[o + 1] = h1;
    qb[o + 4194304] = l0; qb[o + 4194305] = l1;
  } else if (c < 2560) {
    size_t o = (size_t)t * 512 + (c - 2048);
    kb[o] = h0; kb[o + 1] = h1;
    kb[o + 1048576] = l0; kb[o + 1048577] = l1;
  } else {
    int d = c - 2560;
    int kv = d >> 7, dI = d & 127, bq = t >> 9;
    size_t o = (((size_t)(bq * 4 + kv) * 128 + dI) << 9) + s;
    vT[o] = h0; vT[o + 512] = h1;
    vT[o + 1048576] = l0; vT[o + 1048576 + 512] = l1;
  }
}

// out = P0 + P1 + res (f32, float4); works in-place when res==out
__global__ void k_add2res(const float* __restrict__ P, const float* __restrict__ res,
                          float* __restrict__ out){
  int i = (blockIdx.x * 256 + threadIdx.x) * 4;
  float4 a = *(const float4*)(P + i);
  float4 b = *(const float4*)(P + 4194304 + i);
  float4 r = *(const float4*)(res + i);
  float4 o; o.x = a.x + b.x + r.x; o.y = a.y + b.y + r.y;
  o.z = a.z + b.z + r.z; o.w = a.w + b.w + r.w;
  *(float4*)(out + i) = o;
}

// f32 causal softmax, in-place repack to P hi/lo halves per 1024-ushort row
__global__ void k_softmax(float* __restrict__ sp){
  int row = blockIdx.x;
  int s = row & 511;
  float* in = sp + (size_t)row * 512;
  unsigned short* op = (unsigned short*)in;
  int t0 = threadIdx.x, t1 = threadIdx.x + 256;
  const float scale = 0.088388347648318447f;
  float v0 = (t0 <= s) ? in[t0] * scale : -3.0e38f;
  float v1 = (t1 <= s) ? in[t1] * scale : -3.0e38f;
  float mx = fmaxf(v0, v1);
#pragma unroll
  for (int o = 32; o; o >>= 1) mx = fmaxf(mx, __shfl_xor(mx, o));
  __shared__ float sred[8];
  int lane = threadIdx.x & 63, wid = threadIdx.x >> 6;
  if (lane == 0) sred[wid] = mx;
  __syncthreads();
  mx = fmaxf(fmaxf(sred[0], sred[1]), fmaxf(sred[2], sred[3]));
  float e0 = (t0 <= s) ? __expf(v0 - mx) : 0.f;
  float e1 = (t1 <= s) ? __expf(v1 - mx) : 0.f;
  float sum = e0 + e1;
#pragma unroll
  for (int o = 32; o; o >>= 1) sum += __shfl_xor(sum, o);
  if (lane == 0) sred[4 + wid] = sum;
  __syncthreads();
  sum = sred[4] + sred[5] + sred[6] + sred[7];
  float inv = 1.f / sum;
  float p0 = e0 * inv, p1 = e1 * inv;
  unsigned short h0 = f2bf(p0), h1 = f2bf(p1);
  op[t0] = h0; op[512 + t0] = f2bf(p0 - bf2f(h0));
  op[t1] = h1; op[512 + t1] = f2bf(p1 - bf2f(h1));
}

// exact-f32 routing
__global__ void k_route(const float* __restrict__ x2, const float* __restrict__ w,
                        const float* __restrict__ gw, int* __restrict__ eidx,
                        float* __restrict__ ew){
  int t = blockIdx.x; int lane = threadIdx.x;
  const float* row = x2 + (size_t)t * 2048;
  float ss = 0.f;
  for (int d = lane; d < 2048; d += 64){ float v = row[d]; ss += v * v; }
#pragma unroll
  for (int o = 32; o; o >>= 1) ss += __shfl_xor(ss, o);
  float rr = rsqrtf(ss * (1.f/2048.f) + 1e-5f);
  float acc[8] = {0,0,0,0,0,0,0,0};
  for (int d = lane; d < 2048; d += 64){
    float xv = row[d] * rr * w[d];
#pragma unroll
    for (int e = 0; e < 8; ++e) acc[e] += xv * gw[e * 2048 + d];
  }
#pragma unroll
  for (int e = 0; e < 8; ++e)
#pragma unroll
    for (int o = 32; o; o >>= 1) acc[e] += __shfl_xor(acc[e], o);
  if (lane == 0){
    int i0 = 0;
#pragma unroll
    for (int e = 1; e < 8; ++e) if (acc[e] > acc[i0]) i0 = e;
    int i1 = -1;
#pragma unroll
    for (int e = 0; e < 8; ++e) if (e != i0 && (i1 < 0 || acc[e] > acc[i1])) i1 = e;
    float p1 = __expf(acc[i1] - acc[i0]);
    float inv = 1.f / (1.f + p1);
    eidx[t * 2 + 0] = i0; eidx[t * 2 + 1] = i1;
    ew[t * 2 + 0] = inv;  ew[t * 2 + 1] = p1 * inv;
  }
}

__global__ void k_zero(float* __restrict__ p){
  p[(size_t)blockIdx.x * 256 + threadIdx.x] = 0.f;
}

__global__ void k_ubuild(const float* __restrict__ U1, const float* __restrict__ U3,
                         const int* __restrict__ eidx,
                         unsigned short* __restrict__ u10, unsigned short* __restrict__ u11,
                         unsigned short* __restrict__ u30, unsigned short* __restrict__ u31){
  int idx = blockIdx.x * 256 + threadIdx.x;
  int t = idx >> 7, j = idx & 127; int e = j >> 4;
  int e0 = eidx[t * 2], e1 = eidx[t * 2 + 1];
  float v1 = U1[idx] * 2.0f, v3 = U3[idx] * 2.0f;
  u10[idx] = (e == e0) ? f2bf(v1) : (unsigned short)0;
  u11[idx] = (e == e1) ? f2bf(v1) : (unsigned short)0;
  u30[idx] = (e == e0) ? f2bf(v3) : (unsigned short)0;
  u31[idx] = (e == e1) ? f2bf(v3) : (unsigned short)0;
}

__global__ void k_addip(unsigned short* __restrict__ a, const unsigned short* __restrict__ b){
  size_t i = (size_t)blockIdx.x * 256 + threadIdx.x;
  a[i] = f2bf(bf2f(a[i]) + bf2f(b[i]));
}

__global__ void k_vhat(const float* __restrict__ U20, const float* __restrict__ U21,
                       const int* __restrict__ eidx, unsigned short* __restrict__ out){
  int idx = blockIdx.x * 256 + threadIdx.x;
  int t = idx >> 7, j = idx & 127; int e = j >> 4;
  int e0 = eidx[t * 2], e1 = eidx[t * 2 + 1];
  float v = 0.f;
  if (e == e0) v = 2.0f * U20[idx];
  else if (e == e1) v = 2.0f * U21[idx];
  out[idx] = f2bf(v);
}

// ---------------------------------------------------------------------------
extern "C" void kernel_launch(void* const* d_in, const int* in_sizes, int n_in,
                              void* d_out, int out_size, void* d_ws, size_t ws_size,
                              hipStream_t stream){
  const float* data  = (const float*)d_in[0];
  const float* rcos  = (const float*)d_in[2];
  const float* rsin  = (const float*)d_in[3];
  const float* attw  = (const float*)d_in[4];
  const float* ffnw  = (const float*)d_in[5];
  const float* wq    = (const float*)d_in[6];
  const float* wk    = (const float*)d_in[7];
  const float* wv    = (const float*)d_in[8];
  const float* wo    = (const float*)d_in[9];
  const float* lqA   = (const float*)d_in[10];
  const float* lqB   = (const float*)d_in[11];
  const float* lkA   = (const float*)d_in[12];
  const float* lkB   = (const float*)d_in[13];
  const float* lvA   = (const float*)d_in[14];
  const float* lvB   = (const float*)d_in[15];
  const float* loA   = (const float*)d_in[16];
  const float* loB   = (const float*)d_in[17];
  const float* w1    = (const float*)d_in[18];
  const float* w2    = (const float*)d_in[19];
  const float* w3    = (const float*)d_in[20];
  const float* gatew = (const float*)d_in[21];
  const float* eA1   = (const float*)d_in[22];
  const float* eB1   = (const float*)d_in[23];
  const float* eA2   = (const float*)d_in[24];
  const float* eB2   = (const float*)d_in[25];
  const float* eA3   = (const float*)d_in[26];
  const float* eB3   = (const float*)d_in[27];
  (void)in_sizes; (void)n_in; (void)out_size; (void)ws_size;

  char* base = (char*)d_ws;
  float* data2 = (float*)d_out;  // residual stream f32 [2048][2048]

  // ---- attention arena (phase-overlaid byte offsets) ----
  unsigned short* hb   = (unsigned short*)(base + 0);         // pair 16.8 MB
  unsigned short* Wqkv = (unsigned short*)(base + 16777216);  // pair [3072][2048] 25.2 MB
  float*          QKVf = (float*)(base + 41943040);           // [2][2048][3072] 50.3 MB -> end 92.3 MB
  unsigned short* qb   = (unsigned short*)(base + 92274688);  // pair 16.8 MB
  unsigned short* kb   = (unsigned short*)(base + 109051904); // pair 4.2 MB
  unsigned short* vT   = (unsigned short*)(base + 113246208); // pair 4.2 MB -> end 117.4 MB
  float*          sc   = (float*)(base + 0);                  // 67.1 MB (after QKV epi)
  unsigned short* scU  = (unsigned short*)(base + 0);
  unsigned short* ao   = (unsigned short*)(base + 67108864);  // pair 16.8 MB (over dead QKVf tail)
  unsigned short* Wo   = (unsigned short*)(base + 0);         // pair 16.8 MB (after PV)
  float*          Wof  = (float*)(base + 16777216);           // [2][2048][2048] 33.6 MB

  // ---- FFN arena (attention fully dead) ----
  size_t off = 0;
  auto alloc = [&](size_t n)->char*{ char* p = base + off; off = (off + n + 255) & ~(size_t)255; return p; };
  int*   eidx = (int*)alloc(16384);
  float* ew   = (float*)alloc(16384);
  unsigned short* hnb  = (unsigned short*)alloc(8388608);
  unsigned short* h1b  = (unsigned short*)alloc(23068672);   // later gh1, later W2f
  unsigned short* h3b  = (unsigned short*)alloc(23068672);
  unsigned short* wbuf = (unsigned short*)alloc(23068672);   // w1 -> w3 -> G1 -> w2
  unsigned short* gh0  = (unsigned short*)alloc(23068672);
  unsigned short* eA1c = (unsigned short*)alloc(524288);
  unsigned short* eA3c = (unsigned short*)alloc(524288);
  unsigned short* eA2c = (unsigned short*)alloc(1441792);
  unsigned short* Bf1  = (unsigned short*)alloc(1441792);
  unsigned short* Bf3  = (unsigned short*)alloc(1441792);
  unsigned short* Bf2  = (unsigned short*)alloc(524288);
  float* Uz = (float*)alloc(4194304);
  float* U1 = Uz, *U3 = Uz + 262144, *U20 = Uz + 524288, *U21 = Uz + 786432;
  unsigned short* Ut10 = (unsigned short*)alloc(524288);
  unsigned short* Ut11 = (unsigned short*)alloc(524288);
  unsigned short* Ut30 = (unsigned short*)alloc(524288);
  unsigned short* Ut31 = (unsigned short*)alloc(524288);
  unsigned short* vhat = (unsigned short*)alloc(524288);
  unsigned short* gh1  = h1b;
  float*          W2f  = (float*)h1b;  // 33.6 MB over h1b+h3b (both dead by then)

  // ================= attention (split hi/lo ~ fp32) =================
  k_rmsnorm<<<2048, 256, 0, stream>>>(data, attw, hb, 4194304);
  k_fold<<<16384, 256, 0, stream>>>(wq, lqB, lqA, Wqkv, 6291456);
  k_fold<<<4096, 256, 0, stream>>>(wk, lkB, lkA, Wqkv + 4194304, 6291456);
  k_fold<<<4096, 256, 0, stream>>>(wv, lvB, lvA, Wqkv + 5242880, 6291456);

  // fused QKV, split-K2 -> f32 partials (256x256 tile: staging traffic halved)
  k_gemm2<256,256,true,8,2><<<dim3(8,12,2), 512, 0, stream>>>(
      hb, 2048, 4194304, Wqkv, 2048, 6291456, QKVf, 3072, 6291456, 32);
  k_qkv_epi<<<12288, 256, 0, stream>>>(QKVf, rcos, rsin, qb, kb, vT);

  k_gemm<0,0,true,true><<<dim3(4,4,64), 256, 0, stream>>>(
      qb, 2048, 128, 1048576, 4194304, kb, 512, 128, 262144, 1048576,
      sc, 512, 262144, 4194304, 0, nullptr,0, nullptr,nullptr,0, 4, 4, 2);
  k_softmax<<<32768, 256, 0, stream>>>(sc);
  k_gemm<5,0,false,true><<<dim3(4,1,64), 256, 0, stream>>>(
      scU, 1024, 524288, 8388608, 512, vT, 512, 65536, 262144, 1048576,
      ao, 2048, 128, 1048576, 4194304, nullptr,0, nullptr,nullptr,0, 16, 4, 2);

  k_fold<<<16384, 256, 0, stream>>>(wo, loB, loA, Wo, 4194304);  // sc dead now
  k_gemm2<256,128,true,8,2><<<dim3(8,16,2), 512, 0, stream>>>(
      ao, 2048, 4194304, Wo, 2048, 4194304, Wof, 2048, 4194304, 32);
  k_add2res<<<4096, 256, 0, stream>>>(Wof, data, data2);

  // ================= FFN (bf16) =================
  k_rmsnorm<<<2048, 256, 0, stream>>>(data2, ffnw, hnb, 0);
  k_route<<<2048, 64, 0, stream>>>(data2, ffnw, gatew, eidx, ew);

  k_cvt4<<<11264, 256, 0, stream>>>(w1, wbuf);
  k_gemm2<256,256,false,1,2><<<dim3(8,22,1), 512, 0, stream>>>(
      hnb, 2048, 0, wbuf, 2048, 0, h1b, 5632, 0, 64);
  k_cvt4<<<11264, 256, 0, stream>>>(w3, wbuf);
  k_gemm2<256,256,false,1,2><<<dim3(8,22,1), 512, 0, stream>>>(
      hnb, 2048, 0, wbuf, 2048, 0, h3b, 5632, 0, 64);

  k_cvt4<<<256, 256, 0, stream>>>(eA1, eA1c);
  k_cvt4<<<256, 256, 0, stream>>>(eA3, eA3c);
  k_cvt4<<<704, 256, 0, stream>>>(eA2, eA2c);
  k_beff<<<2816, 256, 0, stream>>>(eB1, Bf1, 5632);
  k_beff<<<2816, 256, 0, stream>>>(eB3, Bf3, 5632);
  k_beff<<<1024, 256, 0, stream>>>(eB2, Bf2, 2048);
  k_zero<<<4096, 256, 0, stream>>>(Uz);

  k_gemm<2,0,false,false><<<dim3(16,1,8), 256, 0, stream>>>(
      hnb,2048,0,0,0, eA1c,2048,0,0,0, U1,128,0,0,0, nullptr,0, nullptr,nullptr,0, 8,0,0);
  k_gemm<2,0,false,false><<<dim3(16,1,8), 256, 0, stream>>>(
      hnb,2048,0,0,0, eA3c,2048,0,0,0, U3,128,0,0,0, nullptr,0, nullptr,nullptr,0, 8,0,0);
  k_ubuild<<<1024, 256, 0, stream>>>(U1, U3, eidx, Ut10, Ut11, Ut30, Ut31);

  // slot 0
  k_gemm<1,2,false,false><<<dim3(16,44,1), 256, 0, stream>>>(
      Ut10,128,0,0,0, Bf1,128,0,0,0, wbuf,5632,0,0,0, h1b,5632, nullptr,nullptr,0, 4,0,0);
  k_gemm<4,2,false,false><<<dim3(16,44,1), 256, 0, stream>>>(
      Ut30,128,0,0,0, Bf3,128,0,0,0, gh0,5632,0,0,0, h3b,5632, wbuf,ew,0, 4,0,0);
  k_gemm<2,0,false,false><<<dim3(16,1,8), 256, 0, stream>>>(
      gh0,5632,0,0,0, eA2c,5632,0,0,0, U20,128,0,0,0, nullptr,0, nullptr,nullptr,0, 22,0,0);
  // slot 1
  k_gemm<1,2,false,false><<<dim3(16,44,1), 256, 0, stream>>>(
      Ut11,128,0,0,0, Bf1,128,0,0,0, wbuf,5632,0,0,0, h1b,5632, nullptr,nullptr,0, 4,0,0);
  k_gemm<4,2,false,false><<<dim3(16,44,1), 256, 0, stream>>>(
      Ut31,128,0,0,0, Bf3,128,0,0,0, gh1,5632,0,0,0, h3b,5632, wbuf,ew,1, 4,0,0);
  k_gemm<2,0,false,false><<<dim3(16,1,8), 256, 0, stream>>>(
      gh1,5632,0,0,0, eA2c,5632,0,0,0, U21,128,0,0,0, nullptr,0, nullptr,nullptr,0, 22,0,0);

  k_addip<<<45056, 256, 0, stream>>>(gh0, gh1);
  k_vhat<<<1024, 256, 0, stream>>>(U20, U21, eidx, vhat);
  k_gemm<2,0,false,false><<<dim3(16,16,1), 256, 0, stream>>>(
      vhat,128,0,0,0, Bf2,128,0,0,0, data2,2048,0,0,0, nullptr,0, nullptr,nullptr,0, 4,0,0);
  k_cvt4<<<11264, 256, 0, stream>>>(w2, wbuf);
  k_gemm2<128,256,false,8,2><<<dim3(16,8,2), 512, 0, stream>>>(
      gh0, 5632, 0, wbuf, 5632, 0, W2f, 2048, 4194304, 88);
  k_add2res<<<4096, 256, 0, stream>>>(W2f, data2, data2);
}

// Round 4
// 1027.690 us; speedup vs baseline: 1.0990x; 1.0545x over previous
//
#include <hip/hip_runtime.h>
#include <stdint.h>

#define DI static __device__ __forceinline__

typedef __attribute__((ext_vector_type(8))) short bf16x8;
typedef __attribute__((ext_vector_type(4))) float floatx4;

DI unsigned short f2bf(float x){
  unsigned int u = __float_as_uint(x);
  u += 0x7fffu + ((u >> 16) & 1u);
  return (unsigned short)(u >> 16);
}
DI float bf2f(unsigned short h){ return __uint_as_float(((unsigned int)h) << 16); }

#define GLOAD16(gp, lp) \
  __builtin_amdgcn_global_load_lds((const __attribute__((address_space(1))) unsigned int*)(gp), \
                                   (__attribute__((address_space(3))) unsigned int*)(lp), 16, 0, 0)

#define WAITVM(n) asm volatile("s_waitcnt vmcnt(" #n ")" ::: "memory")

// ---------------------------------------------------------------------------
// bf16 MFMA GEMM: C[M,N] = A[M,K] @ B[N,K]^T (+res), 128x128 tile, BK=32.
// LDS is kept in MFMA-fragment order: staging lane j loads global
// (row=j&15, kchunk=j>>4); fragment read = block*512 + lane*8 -> conflict-free.
// SPLIT: A,B are hi/lo bf16 pairs (lo at +aLo/+bLo elems): 3-pass MFMA ~fp32.
// OUTM: 0=f32 store, 1=bf16 store, 2=f32 atomicAdd (split-K via zb),
//       4=bf16 gh-epilogue (ew*silu(G1)*(acc+res)),
//       5=bf16 hi/lo pair store (+cLo), 6=pair store w/ V-transpose,
//       8=f32 partial store (split-K via zb, partial at zb*sC2)
// RESM: 0=none, 1=f32 residual, 2=bf16 residual (index m*ldr+n)
// CSKIP: skip tiles with blockIdx.y > blockIdx.x (causal)
// batching: zr=z&((1<<zshift)-1), zb=z>>zshift
// ---------------------------------------------------------------------------
template<int OUTM, int RESM, bool CSKIP, bool SPLIT>
__global__ __launch_bounds__(256, 2)
void k_gemm(const unsigned short* __restrict__ A, long lda, long sA1, long sA2, long aLo,
            const unsigned short* __restrict__ B, long ldb, long sB1, long sB2, long bLo,
            void* __restrict__ C, long ldc, long sC1, long sC2, long cLo,
            const void* __restrict__ Rz, long ldr,
            const unsigned short* __restrict__ G1p, const float* __restrict__ ewp, int slot,
            int kIters, int zshift, int bshift)
{
  if (CSKIP && blockIdx.y > blockIdx.x) return;
  __shared__ __attribute__((aligned(16))) unsigned short As[SPLIT ? 8192 : 4096];
  __shared__ __attribute__((aligned(16))) unsigned short Bs[SPLIT ? 8192 : 4096];
  const int tid = threadIdx.x;
  const int w = tid >> 6, lane = tid & 63;
  const int wm = (w >> 1) * 64, wn = (w & 1) * 64;
  const int z = blockIdx.z;
  const int zr = z & ((1 << zshift) - 1);
  const int zb = z >> zshift;
  long k0 = 0;
  if (OUTM == 2 || OUTM == 8) k0 = (long)zb * (long)kIters * 32;
  const unsigned short* Ab = A + (long)((OUTM==8)?0:zb) * sA2 + (long)zr * sA1 + (long)blockIdx.x * 128 * lda + k0;
  const unsigned short* Bb = B + (long)((OUTM==8)?0:zb) * sB2 + (long)(zr >> bshift) * sB1 + (long)blockIdx.y * 128 * ldb + k0;

  // fragment-order staging: lane j -> (row j&15, kchunk j>>4)
  const int rlo = w * 16 + (lane & 15);
  const int rhi = 64 + rlo;
  const int cc  = (lane >> 4) * 8;
  unsigned short* ldsA0 = As + w * 512;
  unsigned short* ldsA1 = As + 2048 + w * 512;
  unsigned short* ldsB0 = Bs + w * 512;
  unsigned short* ldsB1 = Bs + 2048 + w * 512;

  floatx4 acc[4][4];
  floatx4 zv = {0.f, 0.f, 0.f, 0.f};
#pragma unroll
  for (int i = 0; i < 4; ++i)
#pragma unroll
    for (int j = 0; j < 4; ++j) acc[i][j] = zv;

  const int abase = (wm >> 4) * 512 + lane * 8;
  const int bbase = (wn >> 4) * 512 + lane * 8;

  for (int kt = 0; kt < kIters; ++kt) {
    const unsigned short* pa = Ab + (long)kt * 32;
    const unsigned short* pb = Bb + (long)kt * 32;
    GLOAD16(pa + (long)rlo * lda + cc, ldsA0);
    GLOAD16(pa + (long)rhi * lda + cc, ldsA1);
    GLOAD16(pb + (long)rlo * ldb + cc, ldsB0);
    GLOAD16(pb + (long)rhi * ldb + cc, ldsB1);
    if (SPLIT) {
      const unsigned short* pal = pa + aLo;
      const unsigned short* pbl = pb + bLo;
      GLOAD16(pal + (long)rlo * lda + cc, As + 4096 + w * 512);
      GLOAD16(pal + (long)rhi * lda + cc, As + 6144 + w * 512);
      GLOAD16(pbl + (long)rlo * ldb + cc, Bs + 4096 + w * 512);
      GLOAD16(pbl + (long)rhi * ldb + cc, Bs + 6144 + w * 512);
    }
    __syncthreads();
    bf16x8 af[4], bfr[4];
#pragma unroll
    for (int i = 0; i < 4; ++i)
      af[i] = *(const bf16x8*)(As + abase + i * 512);
#pragma unroll
    for (int j = 0; j < 4; ++j)
      bfr[j] = *(const bf16x8*)(Bs + bbase + j * 512);
    if (SPLIT) {
      bf16x8 al[4], bl[4];
#pragma unroll
      for (int i = 0; i < 4; ++i)
        al[i] = *(const bf16x8*)(As + 4096 + abase + i * 512);
#pragma unroll
      for (int j = 0; j < 4; ++j)
        bl[j] = *(const bf16x8*)(Bs + 4096 + bbase + j * 512);
#pragma unroll
      for (int i = 0; i < 4; ++i)
#pragma unroll
        for (int j = 0; j < 4; ++j) {
          acc[i][j] = __builtin_amdgcn_mfma_f32_16x16x32_bf16(af[i], bfr[j], acc[i][j], 0, 0, 0);
          acc[i][j] = __builtin_amdgcn_mfma_f32_16x16x32_bf16(af[i], bl[j], acc[i][j], 0, 0, 0);
          acc[i][j] = __builtin_amdgcn_mfma_f32_16x16x32_bf16(al[i], bfr[j], acc[i][j], 0, 0, 0);
        }
    } else {
#pragma unroll
      for (int i = 0; i < 4; ++i)
#pragma unroll
        for (int j = 0; j < 4; ++j)
          acc[i][j] = __builtin_amdgcn_mfma_f32_16x16x32_bf16(af[i], bfr[j], acc[i][j], 0, 0, 0);
    }
    __syncthreads();
  }

  const long mb = (long)blockIdx.x * 128 + wm + ((lane >> 4) * 4);
  const long nb = (long)blockIdx.y * 128 + wn + (lane & 15);
  const long cbase = (long)zb * sC2 + (long)zr * sC1;
#pragma unroll
  for (int i = 0; i < 4; ++i) {
#pragma unroll
    for (int j = 0; j < 4; ++j) {
#pragma unroll
      for (int rr = 0; rr < 4; ++rr) {
        long m = mb + i * 16 + rr;
        long n = nb + j * 16;
        float v = acc[i][j][rr];
        if (RESM == 1) v += ((const float*)Rz)[m * ldr + n];
        if (RESM == 2) v += bf2f(((const unsigned short*)Rz)[m * ldr + n]);
        if (OUTM == 0 || OUTM == 8) ((float*)C)[cbase + m * ldc + n] = v;
        else if (OUTM == 1) ((unsigned short*)C)[cbase + m * ldc + n] = f2bf(v);
        else if (OUTM == 2) atomicAdd((float*)C + cbase + m * ldc + n, v);
        else if (OUTM == 4) {
          float g1 = bf2f(G1p[m * ldc + n]);
          float s1 = g1 / (1.f + __expf(-g1));
          ((unsigned short*)C)[cbase + m * ldc + n] = f2bf(ewp[m * 2 + slot] * s1 * v);
        } else if (OUTM == 5) {
          unsigned short h = f2bf(v);
          unsigned short l = f2bf(v - bf2f(h));
          ((unsigned short*)C)[cbase + m * ldc + n] = h;
          ((unsigned short*)C)[cbase + m * ldc + n + cLo] = l;
        } else {  // OUTM == 6
          long bq = m >> 9, sI = m & 511, kv = n >> 7, dI = n & 127;
          long t = (((bq * 4 + kv) * 128 + dI) << 9) + sI;
          unsigned short h = f2bf(v);
          unsigned short l = f2bf(v - bf2f(h));
          ((unsigned short*)C)[t] = h;
          ((unsigned short*)C)[t + cLo] = l;
        }
      }
    }
  }
}

// ---------------------------------------------------------------------------
// Big-tile pipelined GEMM: 512 threads / 8 waves (2M x 4N), BK=32, DEPTH-deep
// LDS ring (rotating slots, non-pow2 OK). Tile BM x BN; per-wave (BM/2)x(BN/4).
// Counted vmcnt: stage(kt+DEPTH-1) issued before compute(kt); at the barrier
// wait only for tile kt+1's loads (vmcnt(ahead*LPT)), leaving deeper prefetch
// in flight. DEPTH=2 degenerates to drain-to-0 ping-pong.
// Fragment-order LDS (conflict-free), global_load_lds width=16, setprio.
// OUTM: 1 = bf16 store, 8 = f32 partial store (split-K via blockIdx.z:
//       K-offset zb*kIters*32, C-offset zb*sC2).
// ---------------------------------------------------------------------------
template<int BM, int BN, bool SPLIT, int OUTM, int DEPTH>
__global__ __launch_bounds__(512, 2)
void k_gemm2(const unsigned short* __restrict__ A, long lda, long aLo,
             const unsigned short* __restrict__ B, long ldb, long bLo,
             void* __restrict__ C, long ldc, long sC2, int kIters)
{
  constexpr int ASZ = BM * 32 * (SPLIT ? 2 : 1);   // shorts
  constexpr int BSZ = BN * 32 * (SPLIT ? 2 : 1);
  constexpr int TSZ = ASZ + BSZ;
  constexpr int FM = BM / 32, FN = BN / 64;        // per-wave frag counts
  constexpr int LPT = (SPLIT ? 2 : 1) * (BM / 128 + BN / 128);  // loads/thread/tile
  static_assert(LPT == 3 || LPT == 4 || LPT == 6 || LPT == 8, "vmcnt literals");
  __shared__ __attribute__((aligned(16))) unsigned short sm[DEPTH * TSZ];

  const int tid = threadIdx.x;
  const int w = tid >> 6, lane = tid & 63;
  const int wm = (w >> 2) * (BM / 2), wn = (w & 3) * (BN / 4);
  const int zb = blockIdx.z;
  const long k0 = (OUTM == 8) ? (long)zb * (long)kIters * 32 : 0;
  const unsigned short* Ab = A + (long)blockIdx.x * BM * lda + k0;
  const unsigned short* Bb = B + (long)blockIdx.y * BN * ldb + k0;
  const int rA = lane & 15;
  const int cc = (lane >> 4) * 8;

  floatx4 acc[FM][FN];
  floatx4 zv = {0.f, 0.f, 0.f, 0.f};
#pragma unroll
  for (int i = 0; i < FM; ++i)
#pragma unroll
    for (int j = 0; j < FN; ++j) acc[i][j] = zv;

  // stage tile kt into ring slot sl (fragment order; wave-uniform LDS base)
  auto stage = [&](int kt, int sl) {
    const unsigned short* pa = Ab + (long)kt * 32;
    const unsigned short* pb = Bb + (long)kt * 32;
    unsigned short* sa = sm + (size_t)sl * TSZ;
    unsigned short* sb = sa + ASZ;
#pragma unroll
    for (int r = 0; r < BM / 128; ++r) {
      const int b = r * 8 + w;
      const long row = b * 16 + rA;
      GLOAD16(pa + row * lda + cc, sa + b * 512);
      if (SPLIT) GLOAD16(pa + aLo + row * lda + cc, sa + BM * 32 + b * 512);
    }
#pragma unroll
    for (int r = 0; r < BN / 128; ++r) {
      const int b = r * 8 + w;
      const long row = b * 16 + rA;
      GLOAD16(pb + row * ldb + cc, sb + b * 512);
      if (SPLIT) GLOAD16(pb + bLo + row * ldb + cc, sb + BN * 32 + b * 512);
    }
  };

  // counted pipeline wait: 'ahead' = tiles allowed to remain in flight
  auto waitpipe = [&](int ahead) {
    if (ahead <= 0) { WAITVM(0); return; }
    if (LPT == 3) { if (ahead == 1) { WAITVM(3); } else { WAITVM(6); } }
    else if (LPT == 4) { if (ahead == 1) { WAITVM(4); } else { WAITVM(8); } }
    else if (LPT == 6) { if (ahead == 1) { WAITVM(6); } else { WAITVM(12); } }
    else { if (ahead == 1) { WAITVM(8); } else { WAITVM(16); } }
  };

  // prologue: stage DEPTH-1 tiles ahead, wait for tile 0 only
  int np = DEPTH - 1; if (np > kIters) np = kIters;
  for (int p = 0; p < np; ++p) stage(p, p);
  __builtin_amdgcn_sched_barrier(0);
  waitpipe(np - 1);
  __builtin_amdgcn_s_barrier();

  const int aoff = (wm >> 4) * 512 + lane * 8;
  const int boff = (wn >> 4) * 512 + lane * 8;

  int cs = 0;                      // compute slot
  int ss = (np < DEPTH) ? np : 0;  // next stage slot
  for (int kt = 0; kt < kIters; ++kt) {
    if (kt + DEPTH - 1 < kIters) {
      stage(kt + DEPTH - 1, ss);
      ss = (ss + 1 == DEPTH) ? 0 : ss + 1;
    }

    const unsigned short* sa = sm + (size_t)cs * TSZ;
    const unsigned short* sb = sa + ASZ;
    if (SPLIT) {
      bf16x8 bfr[FN], bl[FN];
#pragma unroll
      for (int j = 0; j < FN; ++j) {
        bfr[j] = *(const bf16x8*)(sb + boff + j * 512);
        bl[j]  = *(const bf16x8*)(sb + BN * 32 + boff + j * 512);
      }
      __builtin_amdgcn_s_setprio(1);
#pragma unroll
      for (int i = 0; i < FM; ++i) {
        bf16x8 ai = *(const bf16x8*)(sa + aoff + i * 512);
        bf16x8 ali = *(const bf16x8*)(sa + BM * 32 + aoff + i * 512);
#pragma unroll
        for (int j = 0; j < FN; ++j) {
          acc[i][j] = __builtin_amdgcn_mfma_f32_16x16x32_bf16(ai, bfr[j], acc[i][j], 0, 0, 0);
          acc[i][j] = __builtin_amdgcn_mfma_f32_16x16x32_bf16(ai, bl[j], acc[i][j], 0, 0, 0);
          acc[i][j] = __builtin_amdgcn_mfma_f32_16x16x32_bf16(ali, bfr[j], acc[i][j], 0, 0, 0);
        }
      }
      __builtin_amdgcn_s_setprio(0);
    } else {
      bf16x8 bfr[FN];
#pragma unroll
      for (int j = 0; j < FN; ++j)
        bfr[j] = *(const bf16x8*)(sb + boff + j * 512);
      __builtin_amdgcn_s_setprio(1);
#pragma unroll
      for (int i = 0; i < FM; ++i) {
        bf16x8 ai = *(const bf16x8*)(sa + aoff + i * 512);
#pragma unroll
        for (int j = 0; j < FN; ++j)
          acc[i][j] = __builtin_amdgcn_mfma_f32_16x16x32_bf16(ai, bfr[j], acc[i][j], 0, 0, 0);
      }
      __builtin_amdgcn_s_setprio(0);
    }

    __builtin_amdgcn_sched_barrier(0);
    int ahead = kIters - 2 - kt;
    if (ahead > DEPTH - 2) ahead = DEPTH - 2;
    if (ahead < 0) ahead = 0;
    waitpipe(ahead);
    __builtin_amdgcn_s_barrier();
    cs = (cs + 1 == DEPTH) ? 0 : cs + 1;
  }

  const long mb = (long)blockIdx.x * BM + wm + ((lane >> 4) * 4);
  const long nb = (long)blockIdx.y * BN + wn + (lane & 15);
  const long cbase = (long)zb * sC2;
#pragma unroll
  for (int i = 0; i < FM; ++i) {
#pragma unroll
    for (int j = 0; j < FN; ++j) {
#pragma unroll
      for (int rr = 0; rr < 4; ++rr) {
        long m = mb + i * 16 + rr;
        long n = nb + j * 16;
        float v = acc[i][j][rr];
        if (OUTM == 8) ((float*)C)[cbase + m * ldc + n] = v;
        else ((unsigned short*)C)[m * ldc + n] = f2bf(v);
      }
    }
  }
}

// ---------------------------------------------------------------------------
__global__ void k_rmsnorm(const float* __restrict__ x, const float* __restrict__ w,
                          unsigned short* __restrict__ ob, long loOff){
  int t = blockIdx.x;
  const float* row = x + (size_t)t * 2048;
  float ss = 0.f;
  for (int i = threadIdx.x; i < 2048; i += 256){ float v = row[i]; ss += v * v; }
#pragma unroll
  for (int o = 32; o; o >>= 1) ss += __shfl_xor(ss, o);
  __shared__ float sred[4]; __shared__ float srms;
  int lane = threadIdx.x & 63, wid = threadIdx.x >> 6;
  if (lane == 0) sred[wid] = ss;
  __syncthreads();
  if (threadIdx.x == 0) srms = rsqrtf((sred[0]+sred[1]+sred[2]+sred[3]) * (1.f/2048.f) + 1e-5f);
  __syncthreads();
  float rr = srms;
  for (int i = threadIdx.x; i < 2048; i += 256){
    float v = row[i] * rr * w[i];
    unsigned short h = f2bf(v);
    ob[(size_t)t * 2048 + i] = h;
    if (loOff) ob[(size_t)t * 2048 + i + loOff] = f2bf(v - bf2f(h));
  }
}

// out[n][k] = pair(W[n][k] + 2*sum_r Bm[n][r]*A[r][k]);  K fixed = 2048
__global__ void k_fold(const float* __restrict__ W, const float* __restrict__ Bm,
                       const float* __restrict__ A, unsigned short* __restrict__ out, long loOff){
  int idx = blockIdx.x * 256 + threadIdx.x;
  int n = idx >> 11, k = idx & 2047;
  float acc = W[idx];
  const float* br = Bm + (size_t)n * 16;
#pragma unroll
  for (int r = 0; r < 16; ++r) acc += 2.0f * br[r] * A[r * 2048 + k];
  unsigned short h = f2bf(acc);
  out[idx] = h;
  out[idx + loOff] = f2bf(acc - bf2f(h));
}

__global__ void k_cvt4(const float* __restrict__ in, unsigned short* __restrict__ out){
  int i = (blockIdx.x * 256 + threadIdx.x) * 4;
  float4 v = *(const float4*)(in + i);
  unsigned long long pk = (unsigned long long)f2bf(v.x)
    | ((unsigned long long)f2bf(v.y) << 16)
    | ((unsigned long long)f2bf(v.z) << 32)
    | ((unsigned long long)f2bf(v.w) << 48);
  *(unsigned long long*)(out + i) = pk;
}

// eB [E][F][16] -> out [F][128] with out[f][e*16+r] = eB[e][f][r]
__global__ void k_beff(const float* __restrict__ eB, unsigned short* __restrict__ out, int F){
  int idx = blockIdx.x * 256 + threadIdx.x;
  int f = idx >> 7, er = idx & 127;
  int e = er >> 4, r = er & 15;
  out[idx] = f2bf(eB[((size_t)e * F + f) * 16 + r]);
}

// fused QKV epilogue: sum split-K partials, rope (q,k), pairize, V-transpose
// P: [2][2048][3072] f32. One thread per column-pair.
__global__ void k_qkv_epi(const float* __restrict__ P,
                          const float* __restrict__ rc, const float* __restrict__ rs,
                          unsigned short* __restrict__ qb, unsigned short* __restrict__ kb,
                          unsigned short* __restrict__ vT){
  int idx = blockIdx.x * 256 + threadIdx.x;   // 0 .. 2048*1536-1
  int t = idx / 1536, p = idx - t * 1536;
  int c = p * 2;
  const float2 a = *(const float2*)(P + (size_t)t * 3072 + c);
  const float2 b = *(const float2*)(P + 6291456 + (size_t)t * 3072 + c);
  float v0 = a.x + b.x, v1 = a.y + b.y;
  int s = t & 511;
  if (c < 2560) {
    int i = (c & 127) >> 1;
    float co = rc[s * 64 + i], sn = rs[s * 64 + i];
    float o0 = v0 * co - v1 * sn;
    float o1 = v0 * sn + v1 * co;
    v0 = o0; v1 = o1;
  }
  unsigned short h0 = f2bf(v0), l0 = f2bf(v0 - bf2f(h0));
  unsigned short h1 = f2bf(v1), l1 = f2bf(v1 - bf2f(h1));
  if (c < 2048) {
    size_t o = (size_t)t * 2048 + c;
    qb[o] = h0; qb[o + 1] = h1;
    qb[o + 4194304] = l0; qb[o + 4194305] = l1;
  } else if (c < 2560) {
    size_t o = (size_t)t * 512 + (c - 2048);
    kb[o] = h0; kb[o + 1] = h1;
    kb[o + 1048576] = l0; kb[o + 1048577] = l1;
  } else {
    int d = c - 2560;
    int kv = d >> 7, dI = d & 127, bq = t >> 9;
    size_t o = (((size_t)(bq * 4 + kv) * 128 + dI) << 9) + s;
    vT[o] = h0; vT[o + 512] = h1;
    vT[o + 1048576] = l0; vT[o + 1048576 + 512] = l1;
  }
}

// out = P0 + P1 + res (f32, float4); works in-place when res==out
__global__ void k_add2res(const float* __restrict__ P, const float* __restrict__ res,
                          float* __restrict__ out){
  int i = (blockIdx.x * 256 + threadIdx.x) * 4;
  float4 a = *(const float4*)(P + i);
  float4 b = *(const float4*)(P + 4194304 + i);
  float4 r = *(const float4*)(res + i);
  float4 o; o.x = a.x + b.x + r.x; o.y = a.y + b.y + r.y;
  o.z = a.z + b.z + r.z; o.w = a.w + b.w + r.w;
  *(float4*)(out + i) = o;
}

// f32 causal softmax, in-place repack to P hi/lo halves per 1024-ushort row
__global__ void k_softmax(float* __restrict__ sp){
  int row = blockIdx.x;
  int s = row & 511;
  float* in = sp + (size_t)row * 512;
  unsigned short* op = (unsigned short*)in;
  int t0 = threadIdx.x, t1 = threadIdx.x + 256;
  const float scale = 0.088388347648318447f;
  float v0 = (t0 <= s) ? in[t0] * scale : -3.0e38f;
  float v1 = (t1 <= s) ? in[t1] * scale : -3.0e38f;
  float mx = fmaxf(v0, v1);
#pragma unroll
  for (int o = 32; o; o >>= 1) mx = fmaxf(mx, __shfl_xor(mx, o));
  __shared__ float sred[8];
  int lane = threadIdx.x & 63, wid = threadIdx.x >> 6;
  if (lane == 0) sred[wid] = mx;
  __syncthreads();
  mx = fmaxf(fmaxf(sred[0], sred[1]), fmaxf(sred[2], sred[3]));
  float e0 = (t0 <= s) ? __expf(v0 - mx) : 0.f;
  float e1 = (t1 <= s) ? __expf(v1 - mx) : 0.f;
  float sum = e0 + e1;
#pragma unroll
  for (int o = 32; o; o >>= 1) sum += __shfl_xor(sum, o);
  if (lane == 0) sred[4 + wid] = sum;
  __syncthreads();
  sum = sred[4] + sred[5] + sred[6] + sred[7];
  float inv = 1.f / sum;
  float p0 = e0 * inv, p1 = e1 * inv;
  unsigned short h0 = f2bf(p0), h1 = f2bf(p1);
  op[t0] = h0; op[512 + t0] = f2bf(p0 - bf2f(h0));
  op[t1] = h1; op[512 + t1] = f2bf(p1 - bf2f(h1));
}

// exact-f32 routing
__global__ void k_route(const float* __restrict__ x2, const float* __restrict__ w,
                        const float* __restrict__ gw, int* __restrict__ eidx,
                        float* __restrict__ ew){
  int t = blockIdx.x; int lane = threadIdx.x;
  const float* row = x2 + (size_t)t * 2048;
  float ss = 0.f;
  for (int d = lane; d < 2048; d += 64){ float v = row[d]; ss += v * v; }
#pragma unroll
  for (int o = 32; o; o >>= 1) ss += __shfl_xor(ss, o);
  float rr = rsqrtf(ss * (1.f/2048.f) + 1e-5f);
  float acc[8] = {0,0,0,0,0,0,0,0};
  for (int d = lane; d < 2048; d += 64){
    float xv = row[d] * rr * w[d];
#pragma unroll
    for (int e = 0; e < 8; ++e) acc[e] += xv * gw[e * 2048 + d];
  }
#pragma unroll
  for (int e = 0; e < 8; ++e)
#pragma unroll
    for (int o = 32; o; o >>= 1) acc[e] += __shfl_xor(acc[e], o);
  if (lane == 0){
    int i0 = 0;
#pragma unroll
    for (int e = 1; e < 8; ++e) if (acc[e] > acc[i0]) i0 = e;
    int i1 = -1;
#pragma unroll
    for (int e = 0; e < 8; ++e) if (e != i0 && (i1 < 0 || acc[e] > acc[i1])) i1 = e;
    float p1 = __expf(acc[i1] - acc[i0]);
    float inv = 1.f / (1.f + p1);
    eidx[t * 2 + 0] = i0; eidx[t * 2 + 1] = i1;
    ew[t * 2 + 0] = inv;  ew[t * 2 + 1] = p1 * inv;
  }
}

__global__ void k_zero(float* __restrict__ p){
  p[(size_t)blockIdx.x * 256 + threadIdx.x] = 0.f;
}

__global__ void k_ubuild(const float* __restrict__ U1, const float* __restrict__ U3,
                         const int* __restrict__ eidx,
                         unsigned short* __restrict__ u10, unsigned short* __restrict__ u11,
                         unsigned short* __restrict__ u30, unsigned short* __restrict__ u31){
  int idx = blockIdx.x * 256 + threadIdx.x;
  int t = idx >> 7, j = idx & 127; int e = j >> 4;
  int e0 = eidx[t * 2], e1 = eidx[t * 2 + 1];
  float v1 = U1[idx] * 2.0f, v3 = U3[idx] * 2.0f;
  u10[idx] = (e == e0) ? f2bf(v1) : (unsigned short)0;
  u11[idx] = (e == e1) ? f2bf(v1) : (unsigned short)0;
  u30[idx] = (e == e0) ? f2bf(v3) : (unsigned short)0;
  u31[idx] = (e == e1) ? f2bf(v3) : (unsigned short)0;
}

__global__ void k_addip(unsigned short* __restrict__ a, const unsigned short* __restrict__ b){
  size_t i = (size_t)blockIdx.x * 256 + threadIdx.x;
  a[i] = f2bf(bf2f(a[i]) + bf2f(b[i]));
}

__global__ void k_vhat(const float* __restrict__ U20, const float* __restrict__ U21,
                       const int* __restrict__ eidx, unsigned short* __restrict__ out){
  int idx = blockIdx.x * 256 + threadIdx.x;
  int t = idx >> 7, j = idx & 127; int e = j >> 4;
  int e0 = eidx[t * 2], e1 = eidx[t * 2 + 1];
  float v = 0.f;
  if (e == e0) v = 2.0f * U20[idx];
  else if (e == e1) v = 2.0f * U21[idx];
  out[idx] = f2bf(v);
}

// ---------------------------------------------------------------------------
extern "C" void kernel_launch(void* const* d_in, const int* in_sizes, int n_in,
                              void* d_out, int out_size, void* d_ws, size_t ws_size,
                              hipStream_t stream){
  const float* data  = (const float*)d_in[0];
  const float* rcos  = (const float*)d_in[2];
  const float* rsin  = (const float*)d_in[3];
  const float* attw  = (const float*)d_in[4];
  const float* ffnw  = (const float*)d_in[5];
  const float* wq    = (const float*)d_in[6];
  const float* wk    = (const float*)d_in[7];
  const float* wv    = (const float*)d_in[8];
  const float* wo    = (const float*)d_in[9];
  const float* lqA   = (const float*)d_in[10];
  const float* lqB   = (const float*)d_in[11];
  const float* lkA   = (const float*)d_in[12];
  const float* lkB   = (const float*)d_in[13];
  const float* lvA   = (const float*)d_in[14];
  const float* lvB   = (const float*)d_in[15];
  const float* loA   = (const float*)d_in[16];
  const float* loB   = (const float*)d_in[17];
  const float* w1    = (const float*)d_in[18];
  const float* w2    = (const float*)d_in[19];
  const float* w3    = (const float*)d_in[20];
  const float* gatew = (const float*)d_in[21];
  const float* eA1   = (const float*)d_in[22];
  const float* eB1   = (const float*)d_in[23];
  const float* eA2   = (const float*)d_in[24];
  const float* eB2   = (const float*)d_in[25];
  const float* eA3   = (const float*)d_in[26];
  const float* eB3   = (const float*)d_in[27];
  (void)in_sizes; (void)n_in; (void)out_size; (void)ws_size;

  char* base = (char*)d_ws;
  float* data2 = (float*)d_out;  // residual stream f32 [2048][2048]

  // ---- attention arena (phase-overlaid byte offsets) ----
  unsigned short* hb   = (unsigned short*)(base + 0);         // pair 16.8 MB
  unsigned short* Wqkv = (unsigned short*)(base + 16777216);  // pair [3072][2048] 25.2 MB
  float*          QKVf = (float*)(base + 41943040);           // [2][2048][3072] 50.3 MB -> end 92.3 MB
  unsigned short* qb   = (unsigned short*)(base + 92274688);  // pair 16.8 MB
  unsigned short* kb   = (unsigned short*)(base + 109051904); // pair 4.2 MB
  unsigned short* vT   = (unsigned short*)(base + 113246208); // pair 4.2 MB -> end 117.4 MB
  float*          sc   = (float*)(base + 0);                  // 67.1 MB (after QKV epi)
  unsigned short* scU  = (unsigned short*)(base + 0);
  unsigned short* ao   = (unsigned short*)(base + 67108864);  // pair 16.8 MB (over dead QKVf tail)
  unsigned short* Wo   = (unsigned short*)(base + 0);         // pair 16.8 MB (after PV)
  float*          Wof  = (float*)(base + 16777216);           // [2][2048][2048] 33.6 MB

  // ---- FFN arena (attention fully dead) ----
  size_t off = 0;
  auto alloc = [&](size_t n)->char*{ char* p = base + off; off = (off + n + 255) & ~(size_t)255; return p; };
  int*   eidx = (int*)alloc(16384);
  float* ew   = (float*)alloc(16384);
  unsigned short* hnb  = (unsigned short*)alloc(8388608);
  unsigned short* h1b  = (unsigned short*)alloc(23068672);   // later gh1, later W2f
  unsigned short* h3b  = (unsigned short*)alloc(23068672);
  unsigned short* wbuf = (unsigned short*)alloc(23068672);   // w1 -> w3 -> G1 -> w2
  unsigned short* gh0  = (unsigned short*)alloc(23068672);
  unsigned short* eA1c = (unsigned short*)alloc(524288);
  unsigned short* eA3c = (unsigned short*)alloc(524288);
  unsigned short* eA2c = (unsigned short*)alloc(1441792);
  unsigned short* Bf1  = (unsigned short*)alloc(1441792);
  unsigned short* Bf3  = (unsigned short*)alloc(1441792);
  unsigned short* Bf2  = (unsigned short*)alloc(524288);
  float* Uz = (float*)alloc(4194304);
  float* U1 = Uz, *U3 = Uz + 262144, *U20 = Uz + 524288, *U21 = Uz + 786432;
  unsigned short* Ut10 = (unsigned short*)alloc(524288);
  unsigned short* Ut11 = (unsigned short*)alloc(524288);
  unsigned short* Ut30 = (unsigned short*)alloc(524288);
  unsigned short* Ut31 = (unsigned short*)alloc(524288);
  unsigned short* vhat = (unsigned short*)alloc(524288);
  unsigned short* gh1  = h1b;
  float*          W2f  = (float*)h1b;  // 33.6 MB over h1b+h3b (both dead by then)

  // ================= attention (split hi/lo ~ fp32) =================
  k_rmsnorm<<<2048, 256, 0, stream>>>(data, attw, hb, 4194304);
  k_fold<<<16384, 256, 0, stream>>>(wq, lqB, lqA, Wqkv, 6291456);
  k_fold<<<4096, 256, 0, stream>>>(wk, lkB, lkA, Wqkv + 4194304, 6291456);
  k_fold<<<4096, 256, 0, stream>>>(wv, lvB, lvA, Wqkv + 5242880, 6291456);

  // fused QKV, split-K2 -> f32 partials (256x256 tile, DEPTH=2: 128 KB LDS)
  k_gemm2<256,256,true,8,2><<<dim3(8,12,2), 512, 0, stream>>>(
      hb, 2048, 4194304, Wqkv, 2048, 6291456, QKVf, 3072, 6291456, 32);
  k_qkv_epi<<<12288, 256, 0, stream>>>(QKVf, rcos, rsin, qb, kb, vT);

  k_gemm<0,0,true,true><<<dim3(4,4,64), 256, 0, stream>>>(
      qb, 2048, 128, 1048576, 4194304, kb, 512, 128, 262144, 1048576,
      sc, 512, 262144, 4194304, 0, nullptr,0, nullptr,nullptr,0, 4, 4, 2);
  k_softmax<<<32768, 256, 0, stream>>>(sc);
  k_gemm<5,0,false,true><<<dim3(4,1,64), 256, 0, stream>>>(
      scU, 1024, 524288, 8388608, 512, vT, 512, 65536, 262144, 1048576,
      ao, 2048, 128, 1048576, 4194304, nullptr,0, nullptr,nullptr,0, 16, 4, 2);

  k_fold<<<16384, 256, 0, stream>>>(wo, loB, loA, Wo, 4194304);  // sc dead now
  // Wo: 256x128 SPLIT, DEPTH=3 counted (144 KB LDS), 256 blocks = 1 round
  k_gemm2<256,128,true,8,3><<<dim3(8,16,2), 512, 0, stream>>>(
      ao, 2048, 4194304, Wo, 2048, 4194304, Wof, 2048, 4194304, 32);
  k_add2res<<<4096, 256, 0, stream>>>(Wof, data, data2);

  // ================= FFN (bf16) =================
  k_rmsnorm<<<2048, 256, 0, stream>>>(data2, ffnw, hnb, 0);
  k_route<<<2048, 64, 0, stream>>>(data2, ffnw, gatew, eidx, ew);

  k_cvt4<<<11264, 256, 0, stream>>>(w1, wbuf);
  k_gemm2<256,256,false,1,4><<<dim3(8,22,1), 512, 0, stream>>>(
      hnb, 2048, 0, wbuf, 2048, 0, h1b, 5632, 0, 64);
  k_cvt4<<<11264, 256, 0, stream>>>(w3, wbuf);
  k_gemm2<256,256,false,1,4><<<dim3(8,22,1), 512, 0, stream>>>(
      hnb, 2048, 0, wbuf, 2048, 0, h3b, 5632, 0, 64);

  k_cvt4<<<256, 256, 0, stream>>>(eA1, eA1c);
  k_cvt4<<<256, 256, 0, stream>>>(eA3, eA3c);
  k_cvt4<<<704, 256, 0, stream>>>(eA2, eA2c);
  k_beff<<<2816, 256, 0, stream>>>(eB1, Bf1, 5632);
  k_beff<<<2816, 256, 0, stream>>>(eB3, Bf3, 5632);
  k_beff<<<1024, 256, 0, stream>>>(eB2, Bf2, 2048);
  k_zero<<<4096, 256, 0, stream>>>(Uz);

  k_gemm<2,0,false,false><<<dim3(16,1,8), 256, 0, stream>>>(
      hnb,2048,0,0,0, eA1c,2048,0,0,0, U1,128,0,0,0, nullptr,0, nullptr,nullptr,0, 8,0,0);
  k_gemm<2,0,false,false><<<dim3(16,1,8), 256, 0, stream>>>(
      hnb,2048,0,0,0, eA3c,2048,0,0,0, U3,128,0,0,0, nullptr,0, nullptr,nullptr,0, 8,0,0);
  k_ubuild<<<1024, 256, 0, stream>>>(U1, U3, eidx, Ut10, Ut11, Ut30, Ut31);

  // slot 0
  k_gemm<1,2,false,false><<<dim3(16,44,1), 256, 0, stream>>>(
      Ut10,128,0,0,0, Bf1,128,0,0,0, wbuf,5632,0,0,0, h1b,5632, nullptr,nullptr,0, 4,0,0);
  k_gemm<4,2,false,false><<<dim3(16,44,1), 256, 0, stream>>>(
      Ut30,128,0,0,0, Bf3,128,0,0,0, gh0,5632,0,0,0, h3b,5632, wbuf,ew,0, 4,0,0);
  k_gemm<2,0,false,false><<<dim3(16,1,8), 256, 0, stream>>>(
      gh0,5632,0,0,0, eA2c,5632,0,0,0, U20,128,0,0,0, nullptr,0, nullptr,nullptr,0, 22,0,0);
  // slot 1
  k_gemm<1,2,false,false><<<dim3(16,44,1), 256, 0, stream>>>(
      Ut11,128,0,0,0, Bf1,128,0,0,0, wbuf,5632,0,0,0, h1b,5632, nullptr,nullptr,0, 4,0,0);
  k_gemm<4,2,false,false><<<dim3(16,44,1), 256, 0, stream>>>(
      Ut31,128,0,0,0, Bf3,128,0,0,0, gh1,5632,0,0,0, h3b,5632, wbuf,ew,1, 4,0,0);
  k_gemm<2,0,false,false><<<dim3(16,1,8), 256, 0, stream>>>(
      gh1,5632,0,0,0, eA2c,5632,0,0,0, U21,128,0,0,0, nullptr,0, nullptr,nullptr,0, 22,0,0);

  k_addip<<<45056, 256, 0, stream>>>(gh0, gh1);
  k_vhat<<<1024, 256, 0, stream>>>(U20, U21, eidx, vhat);
  k_gemm<2,0,false,false><<<dim3(16,16,1), 256, 0, stream>>>(
      vhat,128,0,0,0, Bf2,128,0,0,0, data2,2048,0,0,0, nullptr,0, nullptr,nullptr,0, 4,0,0);
  k_cvt4<<<11264, 256, 0, stream>>>(w2, wbuf);
  // W2: 128x256, DEPTH=4 counted (96 KB LDS), split-K2, 256 blocks
  k_gemm2<128,256,false,8,4><<<dim3(16,8,2), 512, 0, stream>>>(
      gh0, 5632, 0, wbuf, 5632, 0, W2f, 2048, 4194304, 88);
  k_add2res<<<4096, 256, 0, stream>>>(W2f, data2, data2);
}

// Round 5
// 1002.824 us; speedup vs baseline: 1.1262x; 1.0248x over previous
//
#include <hip/hip_runtime.h>
#include <stdint.h>

#define DI static __device__ __forceinline__

typedef __attribute__((ext_vector_type(8))) short bf16x8;
typedef __attribute__((ext_vector_type(4))) float floatx4;

DI unsigned short f2bf(float x){
  unsigned int u = __float_as_uint(x);
  u += 0x7fffu + ((u >> 16) & 1u);
  return (unsigned short)(u >> 16);
}
DI float bf2f(unsigned short h){ return __uint_as_float(((unsigned int)h) << 16); }

#define GLOAD16(gp, lp) \
  __builtin_amdgcn_global_load_lds((const __attribute__((address_space(1))) unsigned int*)(gp), \
                                   (__attribute__((address_space(3))) unsigned int*)(lp), 16, 0, 0)

#define WAITVM(n) asm volatile("s_waitcnt vmcnt(" #n ")" ::: "memory")

// ---------------------------------------------------------------------------
// bf16 MFMA GEMM: C[M,N] = A[M,K] @ B[N,K]^T (+res), 128x128 tile, BK=32.
// LDS is kept in MFMA-fragment order: staging lane j loads global
// (row=j&15, kchunk=j>>4); fragment read = block*512 + lane*8 -> conflict-free.
// SPLIT: A,B are hi/lo bf16 pairs (lo at +aLo/+bLo elems): 3-pass MFMA ~fp32.
// OUTM: 0=f32 store, 1=bf16 store, 2=f32 atomicAdd (split-K via zb),
//       4=bf16 gh-epilogue (ew*silu(G1)*(acc+res)),
//       5=bf16 hi/lo pair store (+cLo), 6=pair store w/ V-transpose,
//       8=f32 partial store (split-K via zb, partial at zb*sC2)
// RESM: 0=none, 1=f32 residual, 2=bf16 residual (index m*ldr+n)
// CSKIP: skip tiles with blockIdx.y > blockIdx.x (causal)
// batching: zr=z&((1<<zshift)-1), zb=z>>zshift
// ---------------------------------------------------------------------------
template<int OUTM, int RESM, bool CSKIP, bool SPLIT>
__global__ __launch_bounds__(256, 2)
void k_gemm(const unsigned short* __restrict__ A, long lda, long sA1, long sA2, long aLo,
            const unsigned short* __restrict__ B, long ldb, long sB1, long sB2, long bLo,
            void* __restrict__ C, long ldc, long sC1, long sC2, long cLo,
            const void* __restrict__ Rz, long ldr,
            const unsigned short* __restrict__ G1p, const float* __restrict__ ewp, int slot,
            int kIters, int zshift, int bshift)
{
  if (CSKIP && blockIdx.y > blockIdx.x) return;
  __shared__ __attribute__((aligned(16))) unsigned short As[SPLIT ? 8192 : 4096];
  __shared__ __attribute__((aligned(16))) unsigned short Bs[SPLIT ? 8192 : 4096];
  const int tid = threadIdx.x;
  const int w = tid >> 6, lane = tid & 63;
  const int wm = (w >> 1) * 64, wn = (w & 1) * 64;
  const int z = blockIdx.z;
  const int zr = z & ((1 << zshift) - 1);
  const int zb = z >> zshift;
  long k0 = 0;
  if (OUTM == 2 || OUTM == 8) k0 = (long)zb * (long)kIters * 32;
  const unsigned short* Ab = A + (long)((OUTM==8)?0:zb) * sA2 + (long)zr * sA1 + (long)blockIdx.x * 128 * lda + k0;
  const unsigned short* Bb = B + (long)((OUTM==8)?0:zb) * sB2 + (long)(zr >> bshift) * sB1 + (long)blockIdx.y * 128 * ldb + k0;

  // fragment-order staging: lane j -> (row j&15, kchunk j>>4)
  const int rlo = w * 16 + (lane & 15);
  const int rhi = 64 + rlo;
  const int cc  = (lane >> 4) * 8;
  unsigned short* ldsA0 = As + w * 512;
  unsigned short* ldsA1 = As + 2048 + w * 512;
  unsigned short* ldsB0 = Bs + w * 512;
  unsigned short* ldsB1 = Bs + 2048 + w * 512;

  floatx4 acc[4][4];
  floatx4 zv = {0.f, 0.f, 0.f, 0.f};
#pragma unroll
  for (int i = 0; i < 4; ++i)
#pragma unroll
    for (int j = 0; j < 4; ++j) acc[i][j] = zv;

  const int abase = (wm >> 4) * 512 + lane * 8;
  const int bbase = (wn >> 4) * 512 + lane * 8;

  for (int kt = 0; kt < kIters; ++kt) {
    const unsigned short* pa = Ab + (long)kt * 32;
    const unsigned short* pb = Bb + (long)kt * 32;
    GLOAD16(pa + (long)rlo * lda + cc, ldsA0);
    GLOAD16(pa + (long)rhi * lda + cc, ldsA1);
    GLOAD16(pb + (long)rlo * ldb + cc, ldsB0);
    GLOAD16(pb + (long)rhi * ldb + cc, ldsB1);
    if (SPLIT) {
      const unsigned short* pal = pa + aLo;
      const unsigned short* pbl = pb + bLo;
      GLOAD16(pal + (long)rlo * lda + cc, As + 4096 + w * 512);
      GLOAD16(pal + (long)rhi * lda + cc, As + 6144 + w * 512);
      GLOAD16(pbl + (long)rlo * ldb + cc, Bs + 4096 + w * 512);
      GLOAD16(pbl + (long)rhi * ldb + cc, Bs + 6144 + w * 512);
    }
    __syncthreads();
    bf16x8 af[4], bfr[4];
#pragma unroll
    for (int i = 0; i < 4; ++i)
      af[i] = *(const bf16x8*)(As + abase + i * 512);
#pragma unroll
    for (int j = 0; j < 4; ++j)
      bfr[j] = *(const bf16x8*)(Bs + bbase + j * 512);
    if (SPLIT) {
      bf16x8 al[4], bl[4];
#pragma unroll
      for (int i = 0; i < 4; ++i)
        al[i] = *(const bf16x8*)(As + 4096 + abase + i * 512);
#pragma unroll
      for (int j = 0; j < 4; ++j)
        bl[j] = *(const bf16x8*)(Bs + 4096 + bbase + j * 512);
#pragma unroll
      for (int i = 0; i < 4; ++i)
#pragma unroll
        for (int j = 0; j < 4; ++j) {
          acc[i][j] = __builtin_amdgcn_mfma_f32_16x16x32_bf16(af[i], bfr[j], acc[i][j], 0, 0, 0);
          acc[i][j] = __builtin_amdgcn_mfma_f32_16x16x32_bf16(af[i], bl[j], acc[i][j], 0, 0, 0);
          acc[i][j] = __builtin_amdgcn_mfma_f32_16x16x32_bf16(al[i], bfr[j], acc[i][j], 0, 0, 0);
        }
    } else {
#pragma unroll
      for (int i = 0; i < 4; ++i)
#pragma unroll
        for (int j = 0; j < 4; ++j)
          acc[i][j] = __builtin_amdgcn_mfma_f32_16x16x32_bf16(af[i], bfr[j], acc[i][j], 0, 0, 0);
    }
    __syncthreads();
  }

  const long mb = (long)blockIdx.x * 128 + wm + ((lane >> 4) * 4);
  const long nb = (long)blockIdx.y * 128 + wn + (lane & 15);
  const long cbase = (long)zb * sC2 + (long)zr * sC1;
#pragma unroll
  for (int i = 0; i < 4; ++i) {
#pragma unroll
    for (int j = 0; j < 4; ++j) {
#pragma unroll
      for (int rr = 0; rr < 4; ++rr) {
        long m = mb + i * 16 + rr;
        long n = nb + j * 16;
        float v = acc[i][j][rr];
        if (RESM == 1) v += ((const float*)Rz)[m * ldr + n];
        if (RESM == 2) v += bf2f(((const unsigned short*)Rz)[m * ldr + n]);
        if (OUTM == 0 || OUTM == 8) ((float*)C)[cbase + m * ldc + n] = v;
        else if (OUTM == 1) ((unsigned short*)C)[cbase + m * ldc + n] = f2bf(v);
        else if (OUTM == 2) atomicAdd((float*)C + cbase + m * ldc + n, v);
        else if (OUTM == 4) {
          float g1 = bf2f(G1p[m * ldc + n]);
          float s1 = g1 / (1.f + __expf(-g1));
          ((unsigned short*)C)[cbase + m * ldc + n] = f2bf(ewp[m * 2 + slot] * s1 * v);
        } else if (OUTM == 5) {
          unsigned short h = f2bf(v);
          unsigned short l = f2bf(v - bf2f(h));
          ((unsigned short*)C)[cbase + m * ldc + n] = h;
          ((unsigned short*)C)[cbase + m * ldc + n + cLo] = l;
        } else {  // OUTM == 6
          long bq = m >> 9, sI = m & 511, kv = n >> 7, dI = n & 127;
          long t = (((bq * 4 + kv) * 128 + dI) << 9) + sI;
          unsigned short h = f2bf(v);
          unsigned short l = f2bf(v - bf2f(h));
          ((unsigned short*)C)[t] = h;
          ((unsigned short*)C)[t + cLo] = l;
        }
      }
    }
  }
}

// ---------------------------------------------------------------------------
// Big-tile pipelined GEMM: 512 threads / 8 waves (2M x 4N), BK=32, DEPTH-deep
// LDS ring (rotating slots). Tile BM x BN; per-wave (BM/2)x(BN/4).
// Counted vmcnt: stage(kt+DEPTH-1) issued before compute(kt); at the barrier
// wait only for tile kt+1's loads (vmcnt(ahead*LPT)), leaving deeper prefetch
// in flight. DEPTH=2 degenerates to drain-to-0 ping-pong.
// BN may be a non-multiple of 128 ONLY at DEPTH=2 (guarded staging rounds give
// waves asymmetric load counts; drain-to-0 vmcnt is per-wave so that's safe).
// Fragment-order LDS (conflict-free), global_load_lds width=16, setprio.
// OUTM: 1 = bf16 store, 8 = f32 partial store (split-K via blockIdx.z:
//       K-offset zb*kIters*32, C-offset zb*sC2).
// ---------------------------------------------------------------------------
template<int BM, int BN, bool SPLIT, int OUTM, int DEPTH>
__global__ __launch_bounds__(512, 2)
void k_gemm2(const unsigned short* __restrict__ A, long lda, long aLo,
             const unsigned short* __restrict__ B, long ldb, long bLo,
             void* __restrict__ C, long ldc, long sC2, int kIters)
{
  constexpr int ASZ = BM * 32 * (SPLIT ? 2 : 1);   // shorts
  constexpr int BSZ = BN * 32 * (SPLIT ? 2 : 1);
  constexpr int TSZ = ASZ + BSZ;
  constexpr int FM = BM / 32, FN = BN / 64;        // per-wave frag counts
  constexpr int LPT = (SPLIT ? 2 : 1) * (BM / 128 + BN / 128);  // loads/thread/tile
  static_assert((BM % 128 == 0 && BN % 128 == 0) || DEPTH == 2,
                "non-x128 tiles only with drain-to-0 (per-wave vmcnt)");
  static_assert(LPT == 3 || LPT == 4 || LPT == 6 || LPT == 8, "vmcnt literals");
  __shared__ __attribute__((aligned(16))) unsigned short sm[DEPTH * TSZ];

  const int tid = threadIdx.x;
  const int w = tid >> 6, lane = tid & 63;
  const int wm = (w >> 2) * (BM / 2), wn = (w & 3) * (BN / 4);
  const int zb = blockIdx.z;
  const long k0 = (OUTM == 8) ? (long)zb * (long)kIters * 32 : 0;
  const unsigned short* Ab = A + (long)blockIdx.x * BM * lda + k0;
  const unsigned short* Bb = B + (long)blockIdx.y * BN * ldb + k0;
  const int rA = lane & 15;
  const int cc = (lane >> 4) * 8;

  floatx4 acc[FM][FN];
  floatx4 zv = {0.f, 0.f, 0.f, 0.f};
#pragma unroll
  for (int i = 0; i < FM; ++i)
#pragma unroll
    for (int j = 0; j < FN; ++j) acc[i][j] = zv;

  // stage tile kt into ring slot sl (fragment order; wave-uniform LDS base)
  auto stage = [&](int kt, int sl) {
    const unsigned short* pa = Ab + (long)kt * 32;
    const unsigned short* pb = Bb + (long)kt * 32;
    unsigned short* sa = sm + (size_t)sl * TSZ;
    unsigned short* sb = sa + ASZ;
#pragma unroll
    for (int r = 0; r < (BM + 127) / 128; ++r) {
      const int b = r * 8 + w;
      if ((BM & 127) == 0 || b * 16 < BM) {
        const long row = b * 16 + rA;
        GLOAD16(pa + row * lda + cc, sa + b * 512);
        if (SPLIT) GLOAD16(pa + aLo + row * lda + cc, sa + BM * 32 + b * 512);
      }
    }
#pragma unroll
    for (int r = 0; r < (BN + 127) / 128; ++r) {
      const int b = r * 8 + w;
      if ((BN & 127) == 0 || b * 16 < BN) {
        const long row = b * 16 + rA;
        GLOAD16(pb + row * ldb + cc, sb + b * 512);
        if (SPLIT) GLOAD16(pb + bLo + row * ldb + cc, sb + BN * 32 + b * 512);
      }
    }
  };

  // counted pipeline wait: 'ahead' = tiles allowed to remain in flight
  auto waitpipe = [&](int ahead) {
    if (ahead <= 0) { WAITVM(0); return; }
    if (LPT == 3) { if (ahead == 1) { WAITVM(3); } else { WAITVM(6); } }
    else if (LPT == 4) { if (ahead == 1) { WAITVM(4); } else { WAITVM(8); } }
    else if (LPT == 6) { if (ahead == 1) { WAITVM(6); } else { WAITVM(12); } }
    else { if (ahead == 1) { WAITVM(8); } else { WAITVM(16); } }
  };

  // prologue: stage DEPTH-1 tiles ahead, wait for tile 0 only
  int np = DEPTH - 1; if (np > kIters) np = kIters;
  for (int p = 0; p < np; ++p) stage(p, p);
  __builtin_amdgcn_sched_barrier(0);
  waitpipe(np - 1);
  __builtin_amdgcn_s_barrier();

  const int aoff = (wm >> 4) * 512 + lane * 8;
  const int boff = (wn >> 4) * 512 + lane * 8;

  int cs = 0;                      // compute slot
  int ss = (np < DEPTH) ? np : 0;  // next stage slot
  for (int kt = 0; kt < kIters; ++kt) {
    if (kt + DEPTH - 1 < kIters) {
      stage(kt + DEPTH - 1, ss);
      ss = (ss + 1 == DEPTH) ? 0 : ss + 1;
    }

    const unsigned short* sa = sm + (size_t)cs * TSZ;
    const unsigned short* sb = sa + ASZ;
    if (SPLIT) {
      bf16x8 bfr[FN], bl[FN];
#pragma unroll
      for (int j = 0; j < FN; ++j) {
        bfr[j] = *(const bf16x8*)(sb + boff + j * 512);
        bl[j]  = *(const bf16x8*)(sb + BN * 32 + boff + j * 512);
      }
      __builtin_amdgcn_s_setprio(1);
#pragma unroll
      for (int i = 0; i < FM; ++i) {
        bf16x8 ai = *(const bf16x8*)(sa + aoff + i * 512);
        bf16x8 ali = *(const bf16x8*)(sa + BM * 32 + aoff + i * 512);
#pragma unroll
        for (int j = 0; j < FN; ++j) {
          acc[i][j] = __builtin_amdgcn_mfma_f32_16x16x32_bf16(ai, bfr[j], acc[i][j], 0, 0, 0);
          acc[i][j] = __builtin_amdgcn_mfma_f32_16x16x32_bf16(ai, bl[j], acc[i][j], 0, 0, 0);
          acc[i][j] = __builtin_amdgcn_mfma_f32_16x16x32_bf16(ali, bfr[j], acc[i][j], 0, 0, 0);
        }
      }
      __builtin_amdgcn_s_setprio(0);
    } else {
      bf16x8 bfr[FN];
#pragma unroll
      for (int j = 0; j < FN; ++j)
        bfr[j] = *(const bf16x8*)(sb + boff + j * 512);
      __builtin_amdgcn_s_setprio(1);
#pragma unroll
      for (int i = 0; i < FM; ++i) {
        bf16x8 ai = *(const bf16x8*)(sa + aoff + i * 512);
#pragma unroll
        for (int j = 0; j < FN; ++j)
          acc[i][j] = __builtin_amdgcn_mfma_f32_16x16x32_bf16(ai, bfr[j], acc[i][j], 0, 0, 0);
      }
      __builtin_amdgcn_s_setprio(0);
    }

    __builtin_amdgcn_sched_barrier(0);
    int ahead = kIters - 2 - kt;
    if (ahead > DEPTH - 2) ahead = DEPTH - 2;
    if (ahead < 0) ahead = 0;
    waitpipe(ahead);
    __builtin_amdgcn_s_barrier();
    cs = (cs + 1 == DEPTH) ? 0 : cs + 1;
  }

  const long mb = (long)blockIdx.x * BM + wm + ((lane >> 4) * 4);
  const long nb = (long)blockIdx.y * BN + wn + (lane & 15);
  const long cbase = (long)zb * sC2;
#pragma unroll
  for (int i = 0; i < FM; ++i) {
#pragma unroll
    for (int j = 0; j < FN; ++j) {
#pragma unroll
      for (int rr = 0; rr < 4; ++rr) {
        long m = mb + i * 16 + rr;
        long n = nb + j * 16;
        float v = acc[i][j][rr];
        if (OUTM == 8) ((float*)C)[cbase + m * ldc + n] = v;
        else ((unsigned short*)C)[m * ldc + n] = f2bf(v);
      }
    }
  }
}

// ---------------------------------------------------------------------------
// Fused expert-slot GEMM: one 128x128 tile pass with TWO accumulator sets.
// acc1 = A1 @ B1^T (lora G1 path), acc3 = A3 @ B3^T (lora G3 path), K=128.
// Epilogue: gh = ew[m][slot] * silu(acc1 + R1[m,n]) * (acc3 + R3[m,n]) -> bf16.
// Replaces the old G1-write + G1-read round-trip (and keeps G1 in f32).
// Fixed geometry: lda=ldb=128, ldc=ldr=5632, kIters=4.
// In-place safe when C aliases R1/R3 (each element read then written by the
// same thread only).
// ---------------------------------------------------------------------------
__global__ __launch_bounds__(256, 2)
void k_gemmdual(const unsigned short* __restrict__ A1, const unsigned short* __restrict__ B1,
                const unsigned short* __restrict__ A3, const unsigned short* __restrict__ B3,
                const unsigned short* __restrict__ R1, const unsigned short* __restrict__ R3,
                unsigned short* __restrict__ C, const float* __restrict__ ewp, int slot)
{
  __shared__ __attribute__((aligned(16))) unsigned short A1s[4096];
  __shared__ __attribute__((aligned(16))) unsigned short A3s[4096];
  __shared__ __attribute__((aligned(16))) unsigned short B1s[4096];
  __shared__ __attribute__((aligned(16))) unsigned short B3s[4096];
  const int tid = threadIdx.x;
  const int w = tid >> 6, lane = tid & 63;
  const int wm = (w >> 1) * 64, wn = (w & 1) * 64;
  const unsigned short* A1b = A1 + (long)blockIdx.x * 128 * 128;
  const unsigned short* A3b = A3 + (long)blockIdx.x * 128 * 128;
  const unsigned short* B1b = B1 + (long)blockIdx.y * 128 * 128;
  const unsigned short* B3b = B3 + (long)blockIdx.y * 128 * 128;
  const int rlo = w * 16 + (lane & 15);
  const int rhi = 64 + rlo;
  const int cc  = (lane >> 4) * 8;

  floatx4 acc1[4][4], acc3[4][4];
  floatx4 zv = {0.f, 0.f, 0.f, 0.f};
#pragma unroll
  for (int i = 0; i < 4; ++i)
#pragma unroll
    for (int j = 0; j < 4; ++j) { acc1[i][j] = zv; acc3[i][j] = zv; }

  const int abase = (wm >> 4) * 512 + lane * 8;
  const int bbase = (wn >> 4) * 512 + lane * 8;

  for (int kt = 0; kt < 4; ++kt) {
    const long ko = (long)kt * 32;
    GLOAD16(A1b + (long)rlo * 128 + ko + cc, A1s + w * 512);
    GLOAD16(A1b + (long)rhi * 128 + ko + cc, A1s + 2048 + w * 512);
    GLOAD16(A3b + (long)rlo * 128 + ko + cc, A3s + w * 512);
    GLOAD16(A3b + (long)rhi * 128 + ko + cc, A3s + 2048 + w * 512);
    GLOAD16(B1b + (long)rlo * 128 + ko + cc, B1s + w * 512);
    GLOAD16(B1b + (long)rhi * 128 + ko + cc, B1s + 2048 + w * 512);
    GLOAD16(B3b + (long)rlo * 128 + ko + cc, B3s + w * 512);
    GLOAD16(B3b + (long)rhi * 128 + ko + cc, B3s + 2048 + w * 512);
    __syncthreads();
    bf16x8 b1f[4], b3f[4];
#pragma unroll
    for (int j = 0; j < 4; ++j) {
      b1f[j] = *(const bf16x8*)(B1s + bbase + j * 512);
      b3f[j] = *(const bf16x8*)(B3s + bbase + j * 512);
    }
#pragma unroll
    for (int i = 0; i < 4; ++i) {
      bf16x8 a1 = *(const bf16x8*)(A1s + abase + i * 512);
      bf16x8 a3 = *(const bf16x8*)(A3s + abase + i * 512);
#pragma unroll
      for (int j = 0; j < 4; ++j) {
        acc1[i][j] = __builtin_amdgcn_mfma_f32_16x16x32_bf16(a1, b1f[j], acc1[i][j], 0, 0, 0);
        acc3[i][j] = __builtin_amdgcn_mfma_f32_16x16x32_bf16(a3, b3f[j], acc3[i][j], 0, 0, 0);
      }
    }
    __syncthreads();
  }

  const long mb = (long)blockIdx.x * 128 + wm + ((lane >> 4) * 4);
  const long nb = (long)blockIdx.y * 128 + wn + (lane & 15);
#pragma unroll
  for (int i = 0; i < 4; ++i) {
#pragma unroll
    for (int j = 0; j < 4; ++j) {
#pragma unroll
      for (int rr = 0; rr < 4; ++rr) {
        long m = mb + i * 16 + rr;
        long n = nb + j * 16;
        float g1 = acc1[i][j][rr] + bf2f(R1[m * 5632 + n]);
        float g3 = acc3[i][j][rr] + bf2f(R3[m * 5632 + n]);
        float s1 = g1 / (1.f + __expf(-g1));
        C[m * 5632 + n] = f2bf(ewp[m * 2 + slot] * s1 * g3);
      }
    }
  }
}

// ---------------------------------------------------------------------------
__global__ void k_rmsnorm(const float* __restrict__ x, const float* __restrict__ w,
                          unsigned short* __restrict__ ob, long loOff){
  int t = blockIdx.x;
  const float* row = x + (size_t)t * 2048;
  float ss = 0.f;
  for (int i = threadIdx.x; i < 2048; i += 256){ float v = row[i]; ss += v * v; }
#pragma unroll
  for (int o = 32; o; o >>= 1) ss += __shfl_xor(ss, o);
  __shared__ float sred[4]; __shared__ float srms;
  int lane = threadIdx.x & 63, wid = threadIdx.x >> 6;
  if (lane == 0) sred[wid] = ss;
  __syncthreads();
  if (threadIdx.x == 0) srms = rsqrtf((sred[0]+sred[1]+sred[2]+sred[3]) * (1.f/2048.f) + 1e-5f);
  __syncthreads();
  float rr = srms;
  for (int i = threadIdx.x; i < 2048; i += 256){
    float v = row[i] * rr * w[i];
    unsigned short h = f2bf(v);
    ob[(size_t)t * 2048 + i] = h;
    if (loOff) ob[(size_t)t * 2048 + i + loOff] = f2bf(v - bf2f(h));
  }
}

// out[n][k] = pair(W[n][k] + 2*sum_r Bm[n][r]*A[r][k]);  K fixed = 2048
__global__ void k_fold(const float* __restrict__ W, const float* __restrict__ Bm,
                       const float* __restrict__ A, unsigned short* __restrict__ out, long loOff){
  int idx = blockIdx.x * 256 + threadIdx.x;
  int n = idx >> 11, k = idx & 2047;
  float acc = W[idx];
  const float* br = Bm + (size_t)n * 16;
#pragma unroll
  for (int r = 0; r < 16; ++r) acc += 2.0f * br[r] * A[r * 2048 + k];
  unsigned short h = f2bf(acc);
  out[idx] = h;
  out[idx + loOff] = f2bf(acc - bf2f(h));
}

__global__ void k_cvt4(const float* __restrict__ in, unsigned short* __restrict__ out){
  int i = (blockIdx.x * 256 + threadIdx.x) * 4;
  float4 v = *(const float4*)(in + i);
  unsigned long long pk = (unsigned long long)f2bf(v.x)
    | ((unsigned long long)f2bf(v.y) << 16)
    | ((unsigned long long)f2bf(v.z) << 32)
    | ((unsigned long long)f2bf(v.w) << 48);
  *(unsigned long long*)(out + i) = pk;
}

// eB [E][F][16] -> out [F][128] with out[f][e*16+r] = eB[e][f][r]
__global__ void k_beff(const float* __restrict__ eB, unsigned short* __restrict__ out, int F){
  int idx = blockIdx.x * 256 + threadIdx.x;
  int f = idx >> 7, er = idx & 127;
  int e = er >> 4, r = er & 15;
  out[idx] = f2bf(eB[((size_t)e * F + f) * 16 + r]);
}

// fused QKV epilogue: sum split-K partials, rope (q,k), pairize, V-transpose
// P: [2][2048][3072] f32. One thread per column-pair.
__global__ void k_qkv_epi(const float* __restrict__ P,
                          const float* __restrict__ rc, const float* __restrict__ rs,
                          unsigned short* __restrict__ qb, unsigned short* __restrict__ kb,
                          unsigned short* __restrict__ vT){
  int idx = blockIdx.x * 256 + threadIdx.x;   // 0 .. 2048*1536-1
  int t = idx / 1536, p = idx - t * 1536;
  int c = p * 2;
  const float2 a = *(const float2*)(P + (size_t)t * 3072 + c);
  const float2 b = *(const float2*)(P + 6291456 + (size_t)t * 3072 + c);
  float v0 = a.x + b.x, v1 = a.y + b.y;
  int s = t & 511;
  if (c < 2560) {
    int i = (c & 127) >> 1;
    float co = rc[s * 64 + i], sn = rs[s * 64 + i];
    float o0 = v0 * co - v1 * sn;
    float o1 = v0 * sn + v1 * co;
    v0 = o0; v1 = o1;
  }
  unsigned short h0 = f2bf(v0), l0 = f2bf(v0 - bf2f(h0));
  unsigned short h1 = f2bf(v1), l1 = f2bf(v1 - bf2f(h1));
  if (c < 2048) {
    size_t o = (size_t)t * 2048 + c;
    qb[o] = h0; qb[o + 1] = h1;
    qb[o + 4194304] = l0; qb[o + 4194305] = l1;
  } else if (c < 2560) {
    size_t o = (size_t)t * 512 + (c - 2048);
    kb[o] = h0; kb[o + 1] = h1;
    kb[o + 1048576] = l0; kb[o + 1048577] = l1;
  } else {
    int d = c - 2560;
    int kv = d >> 7, dI = d & 127, bq = t >> 9;
    size_t o = (((size_t)(bq * 4 + kv) * 128 + dI) << 9) + s;
    vT[o] = h0; vT[o + 512] = h1;
    vT[o + 1048576] = l0; vT[o + 1048576 + 512] = l1;
  }
}

// out = P0 + P1 + res (f32, float4); works in-place when res==out
__global__ void k_add2res(const float* __restrict__ P, const float* __restrict__ res,
                          float* __restrict__ out){
  int i = (blockIdx.x * 256 + threadIdx.x) * 4;
  float4 a = *(const float4*)(P + i);
  float4 b = *(const float4*)(P + 4194304 + i);
  float4 r = *(const float4*)(res + i);
  float4 o; o.x = a.x + b.x + r.x; o.y = a.y + b.y + r.y;
  o.z = a.z + b.z + r.z; o.w = a.w + b.w + r.w;
  *(float4*)(out + i) = o;
}

// f32 causal softmax, in-place repack to P hi/lo halves per 1024-ushort row
__global__ void k_softmax(float* __restrict__ sp){
  int row = blockIdx.x;
  int s = row & 511;
  float* in = sp + (size_t)row * 512;
  unsigned short* op = (unsigned short*)in;
  int t0 = threadIdx.x, t1 = threadIdx.x + 256;
  const float scale = 0.088388347648318447f;
  float v0 = (t0 <= s) ? in[t0] * scale : -3.0e38f;
  float v1 = (t1 <= s) ? in[t1] * scale : -3.0e38f;
  float mx = fmaxf(v0, v1);
#pragma unroll
  for (int o = 32; o; o >>= 1) mx = fmaxf(mx, __shfl_xor(mx, o));
  __shared__ float sred[8];
  int lane = threadIdx.x & 63, wid = threadIdx.x >> 6;
  if (lane == 0) sred[wid] = mx;
  __syncthreads();
  mx = fmaxf(fmaxf(sred[0], sred[1]), fmaxf(sred[2], sred[3]));
  float e0 = (t0 <= s) ? __expf(v0 - mx) : 0.f;
  float e1 = (t1 <= s) ? __expf(v1 - mx) : 0.f;
  float sum = e0 + e1;
#pragma unroll
  for (int o = 32; o; o >>= 1) sum += __shfl_xor(sum, o);
  if (lane == 0) sred[4 + wid] = sum;
  __syncthreads();
  sum = sred[4] + sred[5] + sred[6] + sred[7];
  float inv = 1.f / sum;
  float p0 = e0 * inv, p1 = e1 * inv;
  unsigned short h0 = f2bf(p0), h1 = f2bf(p1);
  op[t0] = h0; op[512 + t0] = f2bf(p0 - bf2f(h0));
  op[t1] = h1; op[512 + t1] = f2bf(p1 - bf2f(h1));
}

// exact-f32 routing
__global__ void k_route(const float* __restrict__ x2, const float* __restrict__ w,
                        const float* __restrict__ gw, int* __restrict__ eidx,
                        float* __restrict__ ew){
  int t = blockIdx.x; int lane = threadIdx.x;
  const float* row = x2 + (size_t)t * 2048;
  float ss = 0.f;
  for (int d = lane; d < 2048; d += 64){ float v = row[d]; ss += v * v; }
#pragma unroll
  for (int o = 32; o; o >>= 1) ss += __shfl_xor(ss, o);
  float rr = rsqrtf(ss * (1.f/2048.f) + 1e-5f);
  float acc[8] = {0,0,0,0,0,0,0,0};
  for (int d = lane; d < 2048; d += 64){
    float xv = row[d] * rr * w[d];
#pragma unroll
    for (int e = 0; e < 8; ++e) acc[e] += xv * gw[e * 2048 + d];
  }
#pragma unroll
  for (int e = 0; e < 8; ++e)
#pragma unroll
    for (int o = 32; o; o >>= 1) acc[e] += __shfl_xor(acc[e], o);
  if (lane == 0){
    int i0 = 0;
#pragma unroll
    for (int e = 1; e < 8; ++e) if (acc[e] > acc[i0]) i0 = e;
    int i1 = -1;
#pragma unroll
    for (int e = 0; e < 8; ++e) if (e != i0 && (i1 < 0 || acc[e] > acc[i1])) i1 = e;
    float p1 = __expf(acc[i1] - acc[i0]);
    float inv = 1.f / (1.f + p1);
    eidx[t * 2 + 0] = i0; eidx[t * 2 + 1] = i1;
    ew[t * 2 + 0] = inv;  ew[t * 2 + 1] = p1 * inv;
  }
}

__global__ void k_zero(float* __restrict__ p){
  p[(size_t)blockIdx.x * 256 + threadIdx.x] = 0.f;
}

__global__ void k_ubuild(const float* __restrict__ U1, const float* __restrict__ U3,
                         const int* __restrict__ eidx,
                         unsigned short* __restrict__ u10, unsigned short* __restrict__ u11,
                         unsigned short* __restrict__ u30, unsigned short* __restrict__ u31){
  int idx = blockIdx.x * 256 + threadIdx.x;
  int t = idx >> 7, j = idx & 127; int e = j >> 4;
  int e0 = eidx[t * 2], e1 = eidx[t * 2 + 1];
  float v1 = U1[idx] * 2.0f, v3 = U3[idx] * 2.0f;
  u10[idx] = (e == e0) ? f2bf(v1) : (unsigned short)0;
  u11[idx] = (e == e1) ? f2bf(v1) : (unsigned short)0;
  u30[idx] = (e == e0) ? f2bf(v3) : (unsigned short)0;
  u31[idx] = (e == e1) ? f2bf(v3) : (unsigned short)0;
}

__global__ void k_addip(unsigned short* __restrict__ a, const unsigned short* __restrict__ b){
  size_t i = (size_t)blockIdx.x * 256 + threadIdx.x;
  a[i] = f2bf(bf2f(a[i]) + bf2f(b[i]));
}

__global__ void k_vhat(const float* __restrict__ U20, const float* __restrict__ U21,
                       const int* __restrict__ eidx, unsigned short* __restrict__ out){
  int idx = blockIdx.x * 256 + threadIdx.x;
  int t = idx >> 7, j = idx & 127; int e = j >> 4;
  int e0 = eidx[t * 2], e1 = eidx[t * 2 + 1];
  float v = 0.f;
  if (e == e0) v = 2.0f * U20[idx];
  else if (e == e1) v = 2.0f * U21[idx];
  out[idx] = f2bf(v);
}

// ---------------------------------------------------------------------------
extern "C" void kernel_launch(void* const* d_in, const int* in_sizes, int n_in,
                              void* d_out, int out_size, void* d_ws, size_t ws_size,
                              hipStream_t stream){
  const float* data  = (const float*)d_in[0];
  const float* rcos  = (const float*)d_in[2];
  const float* rsin  = (const float*)d_in[3];
  const float* attw  = (const float*)d_in[4];
  const float* ffnw  = (const float*)d_in[5];
  const float* wq    = (const float*)d_in[6];
  const float* wk    = (const float*)d_in[7];
  const float* wv    = (const float*)d_in[8];
  const float* wo    = (const float*)d_in[9];
  const float* lqA   = (const float*)d_in[10];
  const float* lqB   = (const float*)d_in[11];
  const float* lkA   = (const float*)d_in[12];
  const float* lkB   = (const float*)d_in[13];
  const float* lvA   = (const float*)d_in[14];
  const float* lvB   = (const float*)d_in[15];
  const float* loA   = (const float*)d_in[16];
  const float* loB   = (const float*)d_in[17];
  const float* w1    = (const float*)d_in[18];
  const float* w2    = (const float*)d_in[19];
  const float* w3    = (const float*)d_in[20];
  const float* gatew = (const float*)d_in[21];
  const float* eA1   = (const float*)d_in[22];
  const float* eB1   = (const float*)d_in[23];
  const float* eA2   = (const float*)d_in[24];
  const float* eB2   = (const float*)d_in[25];
  const float* eA3   = (const float*)d_in[26];
  const float* eB3   = (const float*)d_in[27];
  (void)in_sizes; (void)n_in; (void)out_size; (void)ws_size;

  char* base = (char*)d_ws;
  float* data2 = (float*)d_out;  // residual stream f32 [2048][2048]

  // ---- attention arena (phase-overlaid byte offsets) ----
  unsigned short* hb   = (unsigned short*)(base + 0);         // pair 16.8 MB
  unsigned short* Wqkv = (unsigned short*)(base + 16777216);  // pair [3072][2048] 25.2 MB
  float*          QKVf = (float*)(base + 41943040);           // [2][2048][3072] 50.3 MB -> end 92.3 MB
  unsigned short* qb   = (unsigned short*)(base + 92274688);  // pair 16.8 MB
  unsigned short* kb   = (unsigned short*)(base + 109051904); // pair 4.2 MB
  unsigned short* vT   = (unsigned short*)(base + 113246208); // pair 4.2 MB -> end 117.4 MB
  float*          sc   = (float*)(base + 0);                  // 67.1 MB (after QKV epi)
  unsigned short* scU  = (unsigned short*)(base + 0);
  unsigned short* ao   = (unsigned short*)(base + 67108864);  // pair 16.8 MB (over dead QKVf tail)
  unsigned short* Wo   = (unsigned short*)(base + 0);         // pair 16.8 MB (after PV)
  float*          Wof  = (float*)(base + 16777216);           // [2][2048][2048] 33.6 MB

  // ---- FFN arena (attention fully dead) ----
  size_t off = 0;
  auto alloc = [&](size_t n)->char*{ char* p = base + off; off = (off + n + 255) & ~(size_t)255; return p; };
  int*   eidx = (int*)alloc(16384);
  float* ew   = (float*)alloc(16384);
  unsigned short* hnb  = (unsigned short*)alloc(8388608);
  unsigned short* h1b  = (unsigned short*)alloc(23068672);   // later gh1, later W2f
  unsigned short* h3b  = (unsigned short*)alloc(23068672);
  unsigned short* wbuf = (unsigned short*)alloc(23068672);   // w1 -> w3 -> w2
  unsigned short* gh0  = (unsigned short*)alloc(23068672);
  unsigned short* eA1c = (unsigned short*)alloc(524288);
  unsigned short* eA3c = (unsigned short*)alloc(524288);
  unsigned short* eA2c = (unsigned short*)alloc(1441792);
  unsigned short* Bf1  = (unsigned short*)alloc(1441792);
  unsigned short* Bf3  = (unsigned short*)alloc(1441792);
  unsigned short* Bf2  = (unsigned short*)alloc(524288);
  float* Uz = (float*)alloc(4194304);
  float* U1 = Uz, *U3 = Uz + 262144, *U20 = Uz + 524288, *U21 = Uz + 786432;
  unsigned short* Ut10 = (unsigned short*)alloc(524288);
  unsigned short* Ut11 = (unsigned short*)alloc(524288);
  unsigned short* Ut30 = (unsigned short*)alloc(524288);
  unsigned short* Ut31 = (unsigned short*)alloc(524288);
  unsigned short* vhat = (unsigned short*)alloc(524288);
  unsigned short* gh1  = h1b;
  float*          W2f  = (float*)h1b;  // 33.6 MB over h1b+h3b (both dead by then)

  // ================= attention (split hi/lo ~ fp32) =================
  k_rmsnorm<<<2048, 256, 0, stream>>>(data, attw, hb, 4194304);
  k_fold<<<16384, 256, 0, stream>>>(wq, lqB, lqA, Wqkv, 6291456);
  k_fold<<<4096, 256, 0, stream>>>(wk, lkB, lkA, Wqkv + 4194304, 6291456);
  k_fold<<<4096, 256, 0, stream>>>(wv, lvB, lvA, Wqkv + 5242880, 6291456);

  // fused QKV, split-K2 -> f32 partials. 256x192 tile: grid (8,16,2) = 256
  // blocks = one perfectly-filled CU round (vs 192 blocks at 256x256).
  k_gemm2<256,192,true,8,2><<<dim3(8,16,2), 512, 0, stream>>>(
      hb, 2048, 4194304, Wqkv, 2048, 6291456, QKVf, 3072, 6291456, 32);
  k_qkv_epi<<<12288, 256, 0, stream>>>(QKVf, rcos, rsin, qb, kb, vT);

  k_gemm<0,0,true,true><<<dim3(4,4,64), 256, 0, stream>>>(
      qb, 2048, 128, 1048576, 4194304, kb, 512, 128, 262144, 1048576,
      sc, 512, 262144, 4194304, 0, nullptr,0, nullptr,nullptr,0, 4, 4, 2);
  k_softmax<<<32768, 256, 0, stream>>>(sc);
  k_gemm<5,0,false,true><<<dim3(4,1,64), 256, 0, stream>>>(
      scU, 1024, 524288, 8388608, 512, vT, 512, 65536, 262144, 1048576,
      ao, 2048, 128, 1048576, 4194304, nullptr,0, nullptr,nullptr,0, 16, 4, 2);

  k_fold<<<16384, 256, 0, stream>>>(wo, loB, loA, Wo, 4194304);  // sc dead now
  // Wo: 256x128 SPLIT, DEPTH=3 counted (144 KB LDS), 256 blocks = 1 round
  k_gemm2<256,128,true,8,3><<<dim3(8,16,2), 512, 0, stream>>>(
      ao, 2048, 4194304, Wo, 2048, 4194304, Wof, 2048, 4194304, 32);
  k_add2res<<<4096, 256, 0, stream>>>(Wof, data, data2);

  // ================= FFN (bf16) =================
  k_rmsnorm<<<2048, 256, 0, stream>>>(data2, ffnw, hnb, 0);
  k_route<<<2048, 64, 0, stream>>>(data2, ffnw, gatew, eidx, ew);

  k_cvt4<<<11264, 256, 0, stream>>>(w1, wbuf);
  k_gemm2<256,256,false,1,4><<<dim3(8,22,1), 512, 0, stream>>>(
      hnb, 2048, 0, wbuf, 2048, 0, h1b, 5632, 0, 64);
  k_cvt4<<<11264, 256, 0, stream>>>(w3, wbuf);
  k_gemm2<256,256,false,1,4><<<dim3(8,22,1), 512, 0, stream>>>(
      hnb, 2048, 0, wbuf, 2048, 0, h3b, 5632, 0, 64);

  k_cvt4<<<256, 256, 0, stream>>>(eA1, eA1c);
  k_cvt4<<<256, 256, 0, stream>>>(eA3, eA3c);
  k_cvt4<<<704, 256, 0, stream>>>(eA2, eA2c);
  k_beff<<<2816, 256, 0, stream>>>(eB1, Bf1, 5632);
  k_beff<<<2816, 256, 0, stream>>>(eB3, Bf3, 5632);
  k_beff<<<1024, 256, 0, stream>>>(eB2, Bf2, 2048);
  k_zero<<<4096, 256, 0, stream>>>(Uz);

  k_gemm<2,0,false,false><<<dim3(16,1,8), 256, 0, stream>>>(
      hnb,2048,0,0,0, eA1c,2048,0,0,0, U1,128,0,0,0, nullptr,0, nullptr,nullptr,0, 8,0,0);
  k_gemm<2,0,false,false><<<dim3(16,1,8), 256, 0, stream>>>(
      hnb,2048,0,0,0, eA3c,2048,0,0,0, U3,128,0,0,0, nullptr,0, nullptr,nullptr,0, 8,0,0);
  k_ubuild<<<1024, 256, 0, stream>>>(U1, U3, eidx, Ut10, Ut11, Ut30, Ut31);

  // slot 0: fused G1/G3/silu -> gh0 (G1 stays f32, no wbuf round-trip)
  k_gemmdual<<<dim3(16,44), 256, 0, stream>>>(
      Ut10, Bf1, Ut30, Bf3, h1b, h3b, gh0, ew, 0);
  k_gemm<2,0,false,false><<<dim3(16,1,8), 256, 0, stream>>>(
      gh0,5632,0,0,0, eA2c,5632,0,0,0, U20,128,0,0,0, nullptr,0, nullptr,nullptr,0, 22,0,0);
  // slot 1 (gh1 aliases h1b: in-place safe, each element read-then-written
  // by the same thread)
  k_gemmdual<<<dim3(16,44), 256, 0, stream>>>(
      Ut11, Bf1, Ut31, Bf3, h1b, h3b, gh1, ew, 1);
  k_gemm<2,0,false,false><<<dim3(16,1,8), 256, 0, stream>>>(
      gh1,5632,0,0,0, eA2c,5632,0,0,0, U21,128,0,0,0, nullptr,0, nullptr,nullptr,0, 22,0,0);

  k_addip<<<45056, 256, 0, stream>>>(gh0, gh1);
  k_vhat<<<1024, 256, 0, stream>>>(U20, U21, eidx, vhat);
  k_gemm<2,0,false,false><<<dim3(16,16,1), 256, 0, stream>>>(
      vhat,128,0,0,0, Bf2,128,0,0,0, data2,2048,0,0,0, nullptr,0, nullptr,nullptr,0, 4,0,0);
  k_cvt4<<<11264, 256, 0, stream>>>(w2, wbuf);
  // W2: 128x256, DEPTH=4 counted (96 KB LDS), split-K2, 256 blocks
  k_gemm2<128,256,false,8,4><<<dim3(16,8,2), 512, 0, stream>>>(
      gh0, 5632, 0, wbuf, 5632, 0, W2f, 2048, 4194304, 88);
  k_add2res<<<4096, 256, 0, stream>>>(W2f, data2, data2);
}